// Round 2
// baseline (1837.827 us; speedup 1.0000x reference)
//
#include <hip/hip_runtime.h>
#include <hip/hip_bf16.h>

#define BB   4
#define NN   8192
#define EE   65536
#define FOBS 128
#define FH   256
#define FOUT 1024
#define NLOG 18

// ---------------- degree / dinv ----------------
__global__ void deg_kernel(const int* __restrict__ dst, float* __restrict__ deg, int E) {
    int i = blockIdx.x * blockDim.x + threadIdx.x;
    if (i < E) atomicAdd(&deg[dst[i]], 1.0f);
}

__global__ void dinv_kernel(float* __restrict__ deg, int n) {
    int i = blockIdx.x * blockDim.x + threadIdx.x;
    if (i < n) deg[i] = rsqrtf(deg[i] + 1.0f);   // +1 = self-loop; deg always > 0
}

// ---------------- aggregation: agg = D^-1/2 (A+I) D^-1/2 x ----------------
// self-loop term initializes agg (full overwrite, so no memset needed)
__global__ void self_init_f32(const float* __restrict__ x, const float* __restrict__ dinv,
                              float* __restrict__ agg) {
    int n = blockIdx.x, f = threadIdx.x, F = blockDim.x;
    float w = dinv[n]; w *= w;
    size_t idx = (size_t)n * F + f;
    agg[idx] = x[idx] * w;
}

__global__ void edge_scatter_f32(const float* __restrict__ x, const int* __restrict__ src,
                                 const int* __restrict__ dst, const float* __restrict__ dinv,
                                 float* __restrict__ agg) {
    int e = blockIdx.x, f = threadIdx.x, F = blockDim.x;
    int s = src[e], d = dst[e];
    float w = dinv[s] * dinv[d];
    atomicAdd(&agg[(size_t)d * F + f], x[(size_t)s * F + f] * w);
}

// ---------------- f32 tiled GEMM: C = relu(A @ Bw + bias) ----------------
// A [M,K] f32, Bw [K,N] f32, C [M,N] f32.  BM=BN=64, BK=16, 256 thr, 4x4/thr.
__global__ __launch_bounds__(256) void gemm_bias_relu(
    const float* __restrict__ A, const float* __restrict__ Bw,
    const float* __restrict__ bias, float* __restrict__ C,
    int M, int Nn, int K, int do_relu)
{
    __shared__ float As[16][65];   // [k][m], pad to break store conflicts
    __shared__ float Bs[16][64];   // [k][n]

    int t  = threadIdx.x;
    int bn = blockIdx.x, bm = blockIdx.y;
    int tx = t & 15, ty = t >> 4;
    int r = ty * 4, c = tx * 4;

    float acc[4][4] = {};
    const float* Ab = A + (size_t)bm * 64 * K;
    const float* Bb = Bw + (size_t)bn * 64;

    for (int k0 = 0; k0 < K; k0 += 16) {
        // A tile: 64 rows x 16 k
        {
            int row = t >> 2;
            int kk  = (t & 3) * 4;
            const float* ap = Ab + (size_t)row * K + k0 + kk;
#pragma unroll
            for (int j = 0; j < 4; ++j) As[kk + j][row] = ap[j];
        }
        // B tile: 16 k x 64 n
        {
            int kk  = t >> 4;
            int col = (t & 15) * 4;
            const float* bp = Bb + (size_t)(k0 + kk) * Nn + col;
#pragma unroll
            for (int j = 0; j < 4; ++j) Bs[kk][col + j] = bp[j];
        }
        __syncthreads();
#pragma unroll
        for (int kk = 0; kk < 16; ++kk) {
            float a0 = As[kk][r], a1 = As[kk][r + 1], a2 = As[kk][r + 2], a3 = As[kk][r + 3];
            float b0 = Bs[kk][c], b1 = Bs[kk][c + 1], b2 = Bs[kk][c + 2], b3 = Bs[kk][c + 3];
            acc[0][0] += a0 * b0; acc[0][1] += a0 * b1; acc[0][2] += a0 * b2; acc[0][3] += a0 * b3;
            acc[1][0] += a1 * b0; acc[1][1] += a1 * b1; acc[1][2] += a1 * b2; acc[1][3] += a1 * b3;
            acc[2][0] += a2 * b0; acc[2][1] += a2 * b1; acc[2][2] += a2 * b2; acc[2][3] += a2 * b3;
            acc[3][0] += a3 * b0; acc[3][1] += a3 * b1; acc[3][2] += a3 * b2; acc[3][3] += a3 * b3;
        }
        __syncthreads();
    }

#pragma unroll
    for (int i = 0; i < 4; ++i) {
        int row = bm * 64 + r + i;
#pragma unroll
        for (int j = 0; j < 4; ++j) {
            int col = bn * 64 + c + j;
            float v = acc[i][j] + bias[col];
            if (do_relu) v = fmaxf(v, 0.0f);
            C[(size_t)row * Nn + col] = v;
        }
    }
}

// ---------------- heads: logits = h2 @ Wl + bl ; values = h2 @ Wv + bv ----------------
// 1 wave per node; h2 row (1024 f32) in registers; Wv in LDS; Wl from global (L2-resident, 73KB).
__global__ __launch_bounds__(256) void heads_kernel(
    const float* __restrict__ h2, const float* __restrict__ Wl, const float* __restrict__ bl,
    const float* __restrict__ Wv, const float* __restrict__ bv,
    float* __restrict__ out_logits, float* __restrict__ out_values, int nNodes)
{
    __shared__ float wv_s[FOUT];         // 4 KiB
    for (int i = threadIdx.x; i < FOUT; i += 256) wv_s[i] = Wv[i];
    __syncthreads();

    int lane = threadIdx.x & 63;
    int wid  = threadIdx.x >> 6;

    for (int n = blockIdx.x * 4 + wid; n < nNodes; n += gridDim.x * 4) {
        float h[16];
        const float* hp = h2 + (size_t)n * FOUT;
#pragma unroll
        for (int j = 0; j < 16; ++j) h[j] = hp[lane + 64 * j];

        for (int o = 0; o < NLOG; ++o) {
            float acc = 0.0f;
#pragma unroll
            for (int j = 0; j < 16; ++j)
                acc += h[j] * Wl[(size_t)(lane + 64 * j) * NLOG + o];
            for (int s = 32; s > 0; s >>= 1) acc += __shfl_down(acc, s, 64);
            if (lane == 0)
                out_logits[(size_t)n * NLOG + o] = acc + bl[o];
        }
        {
            float acc = 0.0f;
#pragma unroll
            for (int j = 0; j < 16; ++j)
                acc += h[j] * wv_s[lane + 64 * j];
            for (int s = 32; s > 0; s >>= 1) acc += __shfl_down(acc, s, 64);
            if (lane == 0)
                out_values[n] = acc + bv[0];
        }
    }
}

// ---------------- launcher ----------------
extern "C" void kernel_launch(void* const* d_in, const int* in_sizes, int n_in,
                              void* d_out, int out_size, void* d_ws, size_t ws_size,
                              hipStream_t stream) {
    const float* nodes = (const float*)d_in[0];
    const int*   edges = (const int*)d_in[1];
    const float* W0 = (const float*)d_in[2];
    const float* b0 = (const float*)d_in[3];
    const float* W1 = (const float*)d_in[4];
    const float* b1 = (const float*)d_in[5];
    const float* Wl = (const float*)d_in[6];
    const float* bl = (const float*)d_in[7];
    const float* Wv = (const float*)d_in[8];
    const float* bv = (const float*)d_in[9];

    float* out_logits = (float*)d_out;
    float* out_values = out_logits + (size_t)BB * NN * NLOG;

    char* ws = (char*)d_ws;
    float* dinv = (float*)ws;                                   // 32 KiB
    float* xagg = (float*)(ws + (64 << 10));                    // 4 MiB  [N,128]
    float* h1   = (float*)(ws + (64 << 10) + (4u << 20));       // 8 MiB  [N,256]
    float* hagg = (float*)(ws + (64 << 10) + (12u << 20));      // 8 MiB  [N,256]
    float* h2   = (float*)(ws + (64 << 10) + (20u << 20));      // 32 MiB [N,1024]
    // total ~52.1 MiB, reused across graphs (stream-ordered)

    for (int g = 0; g < BB; ++g) {
        const float* x   = nodes + (size_t)g * NN * FOBS;
        const int*   src = edges + (size_t)g * 2 * EE;
        const int*   dst = src + EE;

        hipMemsetAsync(dinv, 0, NN * sizeof(float), stream);
        deg_kernel<<<(EE + 255) / 256, 256, 0, stream>>>(dst, dinv, EE);
        dinv_kernel<<<NN / 256, 256, 0, stream>>>(dinv, NN);

        // layer 1: h1 = relu((A_hat x) W0 + b0)   [aggregate-then-GEMM]
        self_init_f32<<<NN, FOBS, 0, stream>>>(x, dinv, xagg);
        edge_scatter_f32<<<EE, FOBS, 0, stream>>>(x, src, dst, dinv, xagg);
        gemm_bias_relu<<<dim3(FH / 64, NN / 64), 256, 0, stream>>>(xagg, W0, b0, h1,
                                                                   NN, FH, FOBS, 1);

        // layer 2: h2 = relu((A_hat h1) W1 + b1)
        self_init_f32<<<NN, FH, 0, stream>>>(h1, dinv, hagg);
        edge_scatter_f32<<<EE, FH, 0, stream>>>(h1, src, dst, dinv, hagg);
        gemm_bias_relu<<<dim3(FOUT / 64, NN / 64), 256, 0, stream>>>(hagg, W1, b1, h2,
                                                                     NN, FOUT, FH, 1);

        // heads
        heads_kernel<<<512, 256, 0, stream>>>(h2, Wl, bl, Wv, bv,
                                              out_logits + (size_t)g * NN * NLOG,
                                              out_values + (size_t)g * NN, NN);
    }
}

// Round 3
// 1046.270 us; speedup vs baseline: 1.7566x; 1.7566x over previous
//
#include <hip/hip_runtime.h>
#include <hip/hip_bf16.h>

#define BB   4
#define NN   8192
#define EE   65536
#define FOBS 128
#define FH   256
#define FOUT 1024
#define NLOG 18

// ---------------- degree / dinv ----------------
__global__ void deg_kernel(const int* __restrict__ dst, float* __restrict__ deg, int E) {
    int i = blockIdx.x * blockDim.x + threadIdx.x;
    if (i < E) atomicAdd(&deg[dst[i]], 1.0f);
}

__global__ void dinv_kernel(float* __restrict__ deg, int n) {
    int i = blockIdx.x * blockDim.x + threadIdx.x;
    if (i < n) deg[i] = rsqrtf(deg[i] + 1.0f);   // +1 = self-loop; deg always > 0
}

// ---------------- aggregation: agg = D^-1/2 (A+I) D^-1/2 x ----------------
__global__ void self_init_f32(const float* __restrict__ x, const float* __restrict__ dinv,
                              float* __restrict__ agg) {
    int n = blockIdx.x, f = threadIdx.x, F = blockDim.x;
    float w = dinv[n]; w *= w;
    size_t idx = (size_t)n * F + f;
    agg[idx] = x[idx] * w;
}

__global__ void edge_scatter_f32(const float* __restrict__ x, const int* __restrict__ src,
                                 const int* __restrict__ dst, const float* __restrict__ dinv,
                                 float* __restrict__ agg) {
    int e = blockIdx.x, f = threadIdx.x, F = blockDim.x;
    int s = src[e], d = dst[e];
    float w = dinv[s] * dinv[d];
    atomicAdd(&agg[(size_t)d * F + f], x[(size_t)s * F + f] * w);
}

// ---------------- f32 tiled GEMM: C = relu(A @ Bw + bias) ----------------
__global__ __launch_bounds__(256) void gemm_bias_relu(
    const float* __restrict__ A, const float* __restrict__ Bw,
    const float* __restrict__ bias, float* __restrict__ C,
    int M, int Nn, int K, int do_relu)
{
    __shared__ float As[16][65];
    __shared__ float Bs[16][64];

    int t  = threadIdx.x;
    int bn = blockIdx.x, bm = blockIdx.y;
    int tx = t & 15, ty = t >> 4;
    int r = ty * 4, c = tx * 4;

    float acc[4][4] = {};
    const float* Ab = A + (size_t)bm * 64 * K;
    const float* Bb = Bw + (size_t)bn * 64;

    for (int k0 = 0; k0 < K; k0 += 16) {
        {
            int row = t >> 2;
            int kk  = (t & 3) * 4;
            const float* ap = Ab + (size_t)row * K + k0 + kk;
#pragma unroll
            for (int j = 0; j < 4; ++j) As[kk + j][row] = ap[j];
        }
        {
            int kk  = t >> 4;
            int col = (t & 15) * 4;
            const float* bp = Bb + (size_t)(k0 + kk) * Nn + col;
#pragma unroll
            for (int j = 0; j < 4; ++j) Bs[kk][col + j] = bp[j];
        }
        __syncthreads();
#pragma unroll
        for (int kk = 0; kk < 16; ++kk) {
            float a0 = As[kk][r], a1 = As[kk][r + 1], a2 = As[kk][r + 2], a3 = As[kk][r + 3];
            float b0 = Bs[kk][c], b1 = Bs[kk][c + 1], b2 = Bs[kk][c + 2], b3 = Bs[kk][c + 3];
            acc[0][0] += a0 * b0; acc[0][1] += a0 * b1; acc[0][2] += a0 * b2; acc[0][3] += a0 * b3;
            acc[1][0] += a1 * b0; acc[1][1] += a1 * b1; acc[1][2] += a1 * b2; acc[1][3] += a1 * b3;
            acc[2][0] += a2 * b0; acc[2][1] += a2 * b1; acc[2][2] += a2 * b2; acc[2][3] += a2 * b3;
            acc[3][0] += a3 * b0; acc[3][1] += a3 * b1; acc[3][2] += a3 * b2; acc[3][3] += a3 * b3;
        }
        __syncthreads();
    }

#pragma unroll
    for (int i = 0; i < 4; ++i) {
        int row = bm * 64 + r + i;
#pragma unroll
        for (int j = 0; j < 4; ++j) {
            int col = bn * 64 + c + j;
            float v = acc[i][j] + bias[col];
            if (do_relu) v = fmaxf(v, 0.0f);
            C[(size_t)row * Nn + col] = v;
        }
    }
}

// ---------------- Wl/Wv transpose: WlT[o][k] (o<18 from Wl, o=18 from Wv) ----------------
__global__ void transpose_heads_w(const float* __restrict__ Wl, const float* __restrict__ Wv,
                                  float* __restrict__ WT) {
    int i = blockIdx.x * blockDim.x + threadIdx.x;  // over 19*1024
    if (i < 19 * FOUT) {
        int o = i >> 10, k = i & (FOUT - 1);
        WT[i] = (o < NLOG) ? Wl[(size_t)k * NLOG + o] : Wv[k];
    }
}

// ---------------- heads as tiled GEMM: [8192,1024] @ WT^T[1024,19] ----------------
// 64 nodes/block; h2 tile + W^T chunk in LDS; thread (m = t>>2, ts = t&3) owns
// outputs o = ts + 4*i. Row stride 68 floats = 272 B (16B-aligned for float4,
// bank aliasing <= 2-way which is free).
__global__ __launch_bounds__(256) void heads_gemm(
    const float* __restrict__ h2, const float* __restrict__ WT,
    const float* __restrict__ bl, const float* __restrict__ bv,
    float* __restrict__ out_logits, float* __restrict__ out_values)
{
    __shared__ float hs[64][68];    // 17.4 KiB
    __shared__ float wst[19][68];   //  5.1 KiB

    int t = threadIdx.x;
    int m = t >> 2, ts = t & 3;
    float acc[5] = {};
    const float* hb = h2 + (size_t)blockIdx.x * 64 * FOUT;

    for (int k0 = 0; k0 < FOUT; k0 += 64) {
        // stage h2 tile: 64 rows x 64 k, float4 coalesced
        {
            int c4 = (t & 15) * 4;
            int r  = t >> 4;
#pragma unroll
            for (int i = 0; i < 4; ++i) {
                int row = r + 16 * i;
                float4 v = *(const float4*)(hb + (size_t)row * FOUT + k0 + c4);
                *(float4*)&hs[row][c4] = v;
            }
        }
        // stage W^T chunk: 19 x 64, coalesced rows from WT
        for (int idx = t; idx < 19 * 64; idx += 256) {
            int o = idx >> 6, k = idx & 63;
            wst[o][k] = WT[(size_t)o * FOUT + k0 + k];
        }
        __syncthreads();
#pragma unroll
        for (int k = 0; k < 64; k += 4) {
            float4 hv = *(const float4*)&hs[m][k];
#pragma unroll
            for (int i = 0; i < 5; ++i) {
                int o = ts + 4 * i;
                if (o < 19) {
                    float4 wv = *(const float4*)&wst[o][k];
                    acc[i] += hv.x * wv.x + hv.y * wv.y + hv.z * wv.z + hv.w * wv.w;
                }
            }
        }
        __syncthreads();
    }

    int node = blockIdx.x * 64 + m;
#pragma unroll
    for (int i = 0; i < 5; ++i) {
        int o = ts + 4 * i;
        if (o < NLOG)       out_logits[(size_t)node * NLOG + o] = acc[i] + bl[o];
        else if (o == NLOG) out_values[node] = acc[i] + bv[0];
    }
}

// ---------------- launcher ----------------
extern "C" void kernel_launch(void* const* d_in, const int* in_sizes, int n_in,
                              void* d_out, int out_size, void* d_ws, size_t ws_size,
                              hipStream_t stream) {
    const float* nodes = (const float*)d_in[0];
    const int*   edges = (const int*)d_in[1];
    const float* W0 = (const float*)d_in[2];
    const float* b0 = (const float*)d_in[3];
    const float* W1 = (const float*)d_in[4];
    const float* b1 = (const float*)d_in[5];
    const float* Wl = (const float*)d_in[6];
    const float* bl = (const float*)d_in[7];
    const float* Wv = (const float*)d_in[8];
    const float* bv = (const float*)d_in[9];

    float* out_logits = (float*)d_out;
    float* out_values = out_logits + (size_t)BB * NN * NLOG;

    char* ws = (char*)d_ws;
    float* dinv = (float*)ws;                                   // 32 KiB
    float* WT   = (float*)(ws + (32 << 10));                    // 76 KiB [19,1024]
    float* xagg = (float*)(ws + (256 << 10));                   // 4 MiB  [N,128]
    float* h1   = (float*)(ws + (256 << 10) + (4u << 20));      // 8 MiB  [N,256]
    float* hagg = (float*)(ws + (256 << 10) + (12u << 20));     // 8 MiB  [N,256]
    float* h2   = (float*)(ws + (256 << 10) + (20u << 20));     // 32 MiB [N,1024]

    transpose_heads_w<<<(19 * FOUT + 255) / 256, 256, 0, stream>>>(Wl, Wv, WT);

    for (int g = 0; g < BB; ++g) {
        const float* x   = nodes + (size_t)g * NN * FOBS;
        const int*   src = edges + (size_t)g * 2 * EE;
        const int*   dst = src + EE;

        hipMemsetAsync(dinv, 0, NN * sizeof(float), stream);
        deg_kernel<<<(EE + 255) / 256, 256, 0, stream>>>(dst, dinv, EE);
        dinv_kernel<<<NN / 256, 256, 0, stream>>>(dinv, NN);

        // layer 1: h1 = relu((A_hat x) W0 + b0)
        self_init_f32<<<NN, FOBS, 0, stream>>>(x, dinv, xagg);
        edge_scatter_f32<<<EE, FOBS, 0, stream>>>(x, src, dst, dinv, xagg);
        gemm_bias_relu<<<dim3(FH / 64, NN / 64), 256, 0, stream>>>(xagg, W0, b0, h1,
                                                                   NN, FH, FOBS, 1);

        // layer 2: h2 = relu((A_hat h1) W1 + b1)
        self_init_f32<<<NN, FH, 0, stream>>>(h1, dinv, hagg);
        edge_scatter_f32<<<EE, FH, 0, stream>>>(h1, src, dst, dinv, hagg);
        gemm_bias_relu<<<dim3(FOUT / 64, NN / 64), 256, 0, stream>>>(hagg, W1, b1, h2,
                                                                     NN, FOUT, FH, 1);

        // heads
        heads_gemm<<<NN / 64, 256, 0, stream>>>(h2, WT, bl, bv,
                                                out_logits + (size_t)g * NN * NLOG,
                                                out_values + (size_t)g * NN);
    }
}

// Round 4
// 773.734 us; speedup vs baseline: 2.3753x; 1.3522x over previous
//
#include <hip/hip_runtime.h>
#include <hip/hip_bf16.h>

#define BB   4
#define NN   8192
#define EE   65536
#define FOBS 128
#define FH   256
#define FOUT 1024
#define NLOG 18

typedef __attribute__((ext_vector_type(8))) short frag8;
typedef __attribute__((ext_vector_type(4))) float f32x4;

__device__ __forceinline__ ushort f2b(float v) {
    __hip_bfloat16 h = __float2bfloat16(v);
    return *reinterpret_cast<ushort*>(&h);
}
__device__ __forceinline__ float blo(uint u) { return __uint_as_float(u << 16); }
__device__ __forceinline__ float bhi(uint u) { return __uint_as_float(u & 0xffff0000u); }

// ---------------- degree / dinv ----------------
__global__ void deg_kernel(const int* __restrict__ dst, float* __restrict__ deg, int E) {
    int i = blockIdx.x * blockDim.x + threadIdx.x;
    if (i < E) atomicAdd(&deg[dst[i]], 1.0f);
}

__global__ void dinv_kernel(float* __restrict__ deg, int n) {
    int i = blockIdx.x * blockDim.x + threadIdx.x;
    if (i < n) deg[i] = rsqrtf(deg[i] + 1.0f);   // +1 = self-loop
}

// ---------------- aggregation ----------------
__global__ void self_init_f32(const float* __restrict__ x, const float* __restrict__ dinv,
                              float* __restrict__ agg) {
    int n = blockIdx.x, f = threadIdx.x, F = blockDim.x;
    float w = dinv[n]; w *= w;
    size_t idx = (size_t)n * F + f;
    agg[idx] = x[idx] * w;
}

__global__ void edge_scatter_f32(const float* __restrict__ x, const int* __restrict__ src,
                                 const int* __restrict__ dst, const float* __restrict__ dinv,
                                 float* __restrict__ agg) {
    int e = blockIdx.x, f = threadIdx.x, F = blockDim.x;
    int s = src[e], d = dst[e];
    float w = dinv[s] * dinv[d];
    atomicAdd(&agg[(size_t)d * F + f], x[(size_t)s * F + f] * w);
}

// ---------------- casts / weight prep ----------------
__global__ void cast_f32_bf16(const float* __restrict__ src, ushort* __restrict__ dst, int n4) {
    int i = blockIdx.x * blockDim.x + threadIdx.x;
    if (i < n4) {
        float4 v = *(const float4*)(src + 4 * (size_t)i);
        ushort4 o;
        o.x = f2b(v.x); o.y = f2b(v.y); o.z = f2b(v.z); o.w = f2b(v.w);
        *(ushort4*)(dst + 4 * (size_t)i) = o;
    }
}

// W [K][N] f32 -> WT [N][K] bf16
__global__ void w_transpose_cast(const float* __restrict__ W, ushort* __restrict__ WT,
                                 int K, int N) {
    int i = blockIdx.x * blockDim.x + threadIdx.x;
    if (i < K * N) {
        int n = i / K, k = i - n * K;
        WT[i] = f2b(W[(size_t)k * N + n]);
    }
}

// heads weights: WT2[o][p] packs bf16 pair (k=2p, 2p+1); o<18 from Wl [1024][18], o=18 from Wv
__global__ void pack_heads_w(const float* __restrict__ Wl, const float* __restrict__ Wv,
                             uint* __restrict__ WT2) {
    int i = blockIdx.x * blockDim.x + threadIdx.x;   // over 19*512
    if (i < 19 * 512) {
        int o = i / 512, p = i - o * 512;
        int k0 = 2 * p, k1 = 2 * p + 1;
        float a = (o < NLOG) ? Wl[(size_t)k0 * NLOG + o] : Wv[k0];
        float b = (o < NLOG) ? Wl[(size_t)k1 * NLOG + o] : Wv[k1];
        WT2[i] = (uint)f2b(a) | ((uint)f2b(b) << 16);
    }
}

// ---------------- MFMA GEMM: C = [relu](A @ BT^T + bias) ----------------
// A [M][K] bf16, BT [N][K] bf16, bias f32 [N]. 128x128 tile, BK=64, 4 waves.
__global__ __launch_bounds__(256) void mfma_gemm(
    const ushort* __restrict__ A, const ushort* __restrict__ BT,
    const float* __restrict__ bias,
    float* __restrict__ Cf, ushort* __restrict__ Cb,
    int M, int N, int K, int relu)
{
    __shared__ ushort As[128][72];   // 18 KB, +8 pad
    __shared__ ushort Bs[128][72];   // 18 KB

    int t = threadIdx.x;
    int bn = blockIdx.x, bm = blockIdx.y;
    int lane = t & 63, w = t >> 6;
    int wm = w >> 1, wn = w & 1;
    int l15 = lane & 15, quad = lane >> 4;

    f32x4 acc[4][4] = {};

    int srow = t >> 3, scol = (t & 7) * 8;      // staging: 8 thr/row, 16B each
    const ushort* Abase = A + (size_t)(bm * 128) * K;
    const ushort* Bbase = BT + (size_t)(bn * 128) * K;

    for (int k0 = 0; k0 < K; k0 += 64) {
#pragma unroll
        for (int i = 0; i < 4; ++i) {
            int row = srow + 32 * i;
            *(uint4*)&As[row][scol] = *(const uint4*)(Abase + (size_t)row * K + k0 + scol);
        }
#pragma unroll
        for (int i = 0; i < 4; ++i) {
            int row = srow + 32 * i;
            *(uint4*)&Bs[row][scol] = *(const uint4*)(Bbase + (size_t)row * K + k0 + scol);
        }
        __syncthreads();
#pragma unroll
        for (int kk = 0; kk < 64; kk += 32) {
            frag8 af[4], bf[4];
#pragma unroll
            for (int i = 0; i < 4; ++i)
                af[i] = *(const frag8*)&As[wm * 64 + i * 16 + l15][kk + quad * 8];
#pragma unroll
            for (int j = 0; j < 4; ++j)
                bf[j] = *(const frag8*)&Bs[wn * 64 + j * 16 + l15][kk + quad * 8];
#pragma unroll
            for (int i = 0; i < 4; ++i)
#pragma unroll
                for (int j = 0; j < 4; ++j)
                    acc[i][j] = __builtin_amdgcn_mfma_f32_16x16x32_bf16(af[i], bf[j], acc[i][j], 0, 0, 0);
        }
        __syncthreads();
    }

#pragma unroll
    for (int i = 0; i < 4; ++i) {
#pragma unroll
        for (int j = 0; j < 4; ++j) {
            int col = bn * 128 + wn * 64 + j * 16 + l15;
            float bcol = bias[col];
#pragma unroll
            for (int r = 0; r < 4; ++r) {
                int row = bm * 128 + wm * 64 + i * 16 + quad * 4 + r;
                float v = acc[i][j][r] + bcol;
                if (relu) v = fmaxf(v, 0.0f);
                size_t idx = (size_t)row * N + col;
                if (Cf) Cf[idx] = v;
                if (Cb) Cb[idx] = f2b(v);
            }
        }
    }
}

// ---------------- heads: wave-per-node, WT in LDS (bf16 pairs) ----------------
__global__ __launch_bounds__(256) void heads_bf16(
    const ushort* __restrict__ h2b, const uint* __restrict__ WT2,
    const float* __restrict__ bl, const float* __restrict__ bv,
    float* __restrict__ out_logits, float* __restrict__ out_values, int nNodes)
{
    __shared__ uint wt_s[19 * 512];   // 38 KB
    for (int i = threadIdx.x; i < 19 * 512; i += 256) wt_s[i] = WT2[i];
    __syncthreads();

    int lane = threadIdx.x & 63, w = threadIdx.x >> 6;

    for (int n = blockIdx.x * 4 + w; n < nNodes; n += gridDim.x * 4) {
        const uint* hp = (const uint*)(h2b + (size_t)n * FOUT);
        float2 h[8];
#pragma unroll
        for (int j = 0; j < 8; ++j) {
            uint u = hp[lane + 64 * j];
            h[j].x = blo(u); h[j].y = bhi(u);
        }
        float res = 0.0f;
        for (int o = 0; o < 19; ++o) {
            float s = 0.0f;
#pragma unroll
            for (int j = 0; j < 8; ++j) {
                uint u = wt_s[o * 512 + lane + 64 * j];
                s += h[j].x * blo(u) + h[j].y * bhi(u);
            }
#pragma unroll
            for (int m = 32; m >= 1; m >>= 1) s += __shfl_xor(s, m, 64);
            if (lane == o) res = s;
        }
        if (lane < NLOG)       out_logits[(size_t)n * NLOG + lane] = res + bl[lane];
        else if (lane == NLOG) out_values[n] = res + bv[0];
    }
}

// ---------------- launcher ----------------
extern "C" void kernel_launch(void* const* d_in, const int* in_sizes, int n_in,
                              void* d_out, int out_size, void* d_ws, size_t ws_size,
                              hipStream_t stream) {
    const float* nodes = (const float*)d_in[0];
    const int*   edges = (const int*)d_in[1];
    const float* W0 = (const float*)d_in[2];
    const float* b0 = (const float*)d_in[3];
    const float* W1 = (const float*)d_in[4];
    const float* b1 = (const float*)d_in[5];
    const float* Wl = (const float*)d_in[6];
    const float* bl = (const float*)d_in[7];
    const float* Wv = (const float*)d_in[8];
    const float* bv = (const float*)d_in[9];

    float* out_logits = (float*)d_out;
    float* out_values = out_logits + (size_t)BB * NN * NLOG;

    char* ws = (char*)d_ws;
    float*  dinv   = (float*)(ws);                       // 32 KB
    uint*   WT2    = (uint*)(ws + (64 << 10));           // 38 KB
    ushort* W0T    = (ushort*)(ws + (128 << 10));        // 64 KB  [256][128]
    ushort* W1T    = (ushort*)(ws + (192 << 10));        // 512 KB [1024][256]
    float*  xagg   = (float*)(ws + (1u << 20));          // 4 MB  [N,128]
    ushort* xagg_b = (ushort*)(ws + (5u << 20));         // 2 MB
    float*  hagg   = (float*)(ws + (7u << 20));          // 8 MB  [N,256]
    ushort* hagg_b = (ushort*)(ws + (15u << 20));        // 4 MB
    float*  h1     = (float*)(ws + (19u << 20));         // 8 MB  [N,256]
    ushort* h2b    = (ushort*)(ws + (27u << 20));        // 16 MB [N,1024]
    // total 43 MB

    // weight prep (once per launch)
    w_transpose_cast<<<(FOBS * FH + 255) / 256, 256, 0, stream>>>(W0, W0T, FOBS, FH);
    w_transpose_cast<<<(FH * FOUT + 255) / 256, 256, 0, stream>>>(W1, W1T, FH, FOUT);
    pack_heads_w<<<(19 * 512 + 255) / 256, 256, 0, stream>>>(Wl, Wv, WT2);

    for (int g = 0; g < BB; ++g) {
        const float* x   = nodes + (size_t)g * NN * FOBS;
        const int*   src = edges + (size_t)g * 2 * EE;
        const int*   dst = src + EE;

        hipMemsetAsync(dinv, 0, NN * sizeof(float), stream);
        deg_kernel<<<(EE + 255) / 256, 256, 0, stream>>>(dst, dinv, EE);
        dinv_kernel<<<NN / 256, 256, 0, stream>>>(dinv, NN);

        // layer 1
        self_init_f32<<<NN, FOBS, 0, stream>>>(x, dinv, xagg);
        edge_scatter_f32<<<EE, FOBS, 0, stream>>>(x, src, dst, dinv, xagg);
        cast_f32_bf16<<<(NN * FOBS / 4 + 255) / 256, 256, 0, stream>>>(xagg, xagg_b, NN * FOBS / 4);
        mfma_gemm<<<dim3(FH / 128, NN / 128), 256, 0, stream>>>(
            xagg_b, W0T, b0, h1, (ushort*)nullptr, NN, FH, FOBS, 1);

        // layer 2
        self_init_f32<<<NN, FH, 0, stream>>>(h1, dinv, hagg);
        edge_scatter_f32<<<EE, FH, 0, stream>>>(h1, src, dst, dinv, hagg);
        cast_f32_bf16<<<(NN * FH / 4 + 255) / 256, 256, 0, stream>>>(hagg, hagg_b, NN * FH / 4);
        mfma_gemm<<<dim3(FOUT / 128, NN / 128), 256, 0, stream>>>(
            hagg_b, W1T, b1, (float*)nullptr, h2b, NN, FOUT, FH, 1);

        // heads
        heads_bf16<<<512, 256, 0, stream>>>(h2b, WT2, bl, bv,
                                            out_logits + (size_t)g * NN * NLOG,
                                            out_values + (size_t)g * NN, NN);
    }
}

// Round 6
// 388.056 us; speedup vs baseline: 4.7360x; 1.9939x over previous
//
#include <hip/hip_runtime.h>
#include <hip/hip_bf16.h>

#define BB   4
#define NN   8192
#define EE   65536
#define FOBS 128
#define FH   256
#define FOUT 1024
#define NLOG 18

typedef __attribute__((ext_vector_type(8))) short frag8;
typedef __attribute__((ext_vector_type(4))) float f32x4;

__device__ __forceinline__ ushort f2b(float v) {
    __hip_bfloat16 h = __float2bfloat16(v);
    return *reinterpret_cast<ushort*>(&h);
}
__device__ __forceinline__ float b2f(ushort u) { return __uint_as_float(((uint)u) << 16); }

// ---------------- CSR build ----------------
__global__ void count_kernel(const int* __restrict__ dst, int* __restrict__ cnt, int E) {
    int i = blockIdx.x * blockDim.x + threadIdx.x;
    if (i < E) atomicAdd(&cnt[dst[i]], 1);
}

// single block, 1024 threads, 8 elems/thread: offs/cursor = exclusive scan, dinv = rsqrt(cnt+1)
__global__ __launch_bounds__(1024) void scan_kernel(const int* __restrict__ cnt,
                                                    int* __restrict__ offs,
                                                    int* __restrict__ cursor,
                                                    float* __restrict__ dinv) {
    int t = threadIdx.x;
    int base = t * 8;
    int v[8], s = 0;
#pragma unroll
    for (int j = 0; j < 8; ++j) {
        v[j] = cnt[base + j];
        s += v[j];
        dinv[base + j] = rsqrtf((float)v[j] + 1.0f);
    }
    int lane = t & 63, w = t >> 6;
    int pre = s;
#pragma unroll
    for (int d = 1; d < 64; d <<= 1) {
        int x = __shfl_up(pre, d, 64);
        if (lane >= d) pre += x;
    }
    __shared__ int wsum[16];
    if (lane == 63) wsum[w] = pre;
    __syncthreads();
    if (t == 0) {
        int run = 0;
#pragma unroll
        for (int i = 0; i < 16; ++i) { int tmp = wsum[i]; wsum[i] = run; run += tmp; }
    }
    __syncthreads();
    int excl = wsum[w] + (pre - s);
#pragma unroll
    for (int j = 0; j < 8; ++j) {
        offs[base + j] = excl;
        cursor[base + j] = excl;
        excl += v[j];
    }
    if (t == 1023) offs[NN] = excl;   // offs has NN+1 capacity (own region, no aliasing)
}

__global__ void csr_fill(const int* __restrict__ src, const int* __restrict__ dst,
                         int* __restrict__ cursor, int* __restrict__ csr_src, int E) {
    int e = blockIdx.x * blockDim.x + threadIdx.x;
    if (e < E) {
        int d = dst[e];
        int slot = atomicAdd(&cursor[d], 1);
        csr_src[slot] = src[e];
    }
}

// ---------------- gather aggregation (no atomics), writes bf16 ----------------
// agg[n] = dinv[n]^2 * x[n] + sum_neighbors dinv[s]*dinv[n]*x[s]
__global__ void gather_agg_f32(const float* __restrict__ x, const int* __restrict__ offs,
                               const int* __restrict__ csr_src, const float* __restrict__ dinv,
                               ushort* __restrict__ agg_b, int F) {
    int n = blockIdx.x, f = threadIdx.x;
    float wn = dinv[n];
    float acc = wn * wn * x[(size_t)n * F + f];
    int i0 = offs[n], i1 = offs[n + 1];
    for (int i = i0; i < i1; ++i) {
        int s = csr_src[i];
        acc += dinv[s] * wn * x[(size_t)s * F + f];
    }
    agg_b[(size_t)n * F + f] = f2b(acc);
}

__global__ void gather_agg_bf16(const ushort* __restrict__ xb, const int* __restrict__ offs,
                                const int* __restrict__ csr_src, const float* __restrict__ dinv,
                                ushort* __restrict__ agg_b, int F) {
    int n = blockIdx.x, f = threadIdx.x;
    float wn = dinv[n];
    float acc = wn * wn * b2f(xb[(size_t)n * F + f]);
    int i0 = offs[n], i1 = offs[n + 1];
    for (int i = i0; i < i1; ++i) {
        int s = csr_src[i];
        acc += dinv[s] * wn * b2f(xb[(size_t)s * F + f]);
    }
    agg_b[(size_t)n * F + f] = f2b(acc);
}

// ---------------- weight prep ----------------
// W [K][N] f32 -> WT [N][K] bf16
__global__ void w_transpose_cast(const float* __restrict__ W, ushort* __restrict__ WT,
                                 int K, int N) {
    int i = blockIdx.x * blockDim.x + threadIdx.x;
    if (i < K * N) {
        int n = i / K, k = i - n * K;
        WT[i] = f2b(W[(size_t)k * N + n]);
    }
}

// heads: WT19 [19][1024] bf16, K-major; rows 0..17 = Wl^T, row 18 = Wv
__global__ void pack_heads_w(const float* __restrict__ Wl, const float* __restrict__ Wv,
                             ushort* __restrict__ WT19) {
    int i = blockIdx.x * blockDim.x + threadIdx.x;   // over 19*1024
    if (i < 19 * FOUT) {
        int o = i >> 10, k = i & (FOUT - 1);
        WT19[i] = f2b((o < NLOG) ? Wl[(size_t)k * NLOG + o] : Wv[k]);
    }
}

// ---------------- MFMA GEMM: C = [relu](A @ BT^T + bias) ----------------
// A [M][K] bf16, BT [N][K] bf16, bias f32 [N]. 128x128 tile, BK=64, 4 waves.
__global__ __launch_bounds__(256) void mfma_gemm(
    const ushort* __restrict__ A, const ushort* __restrict__ BT,
    const float* __restrict__ bias,
    float* __restrict__ Cf, ushort* __restrict__ Cb,
    int M, int N, int K, int relu)
{
    __shared__ ushort As[128][72];
    __shared__ ushort Bs[128][72];

    int t = threadIdx.x;
    int bn = blockIdx.x, bm = blockIdx.y;
    int lane = t & 63, w = t >> 6;
    int wm = w >> 1, wn = w & 1;
    int l15 = lane & 15, quad = lane >> 4;

    f32x4 acc[4][4] = {};

    int srow = t >> 3, scol = (t & 7) * 8;
    const ushort* Abase = A + (size_t)(bm * 128) * K;
    const ushort* Bbase = BT + (size_t)(bn * 128) * K;

    for (int k0 = 0; k0 < K; k0 += 64) {
#pragma unroll
        for (int i = 0; i < 4; ++i) {
            int row = srow + 32 * i;
            *(uint4*)&As[row][scol] = *(const uint4*)(Abase + (size_t)row * K + k0 + scol);
        }
#pragma unroll
        for (int i = 0; i < 4; ++i) {
            int row = srow + 32 * i;
            *(uint4*)&Bs[row][scol] = *(const uint4*)(Bbase + (size_t)row * K + k0 + scol);
        }
        __syncthreads();
#pragma unroll
        for (int kk = 0; kk < 64; kk += 32) {
            frag8 af[4], bf[4];
#pragma unroll
            for (int i = 0; i < 4; ++i)
                af[i] = *(const frag8*)&As[wm * 64 + i * 16 + l15][kk + quad * 8];
#pragma unroll
            for (int j = 0; j < 4; ++j)
                bf[j] = *(const frag8*)&Bs[wn * 64 + j * 16 + l15][kk + quad * 8];
#pragma unroll
            for (int i = 0; i < 4; ++i)
#pragma unroll
                for (int j = 0; j < 4; ++j)
                    acc[i][j] = __builtin_amdgcn_mfma_f32_16x16x32_bf16(af[i], bf[j], acc[i][j], 0, 0, 0);
        }
        __syncthreads();
    }

#pragma unroll
    for (int i = 0; i < 4; ++i) {
#pragma unroll
        for (int j = 0; j < 4; ++j) {
            int col = bn * 128 + wn * 64 + j * 16 + l15;
            float bcol = bias[col];
#pragma unroll
            for (int r = 0; r < 4; ++r) {
                int row = bm * 128 + wm * 64 + i * 16 + quad * 4 + r;
                float v = acc[i][j][r] + bcol;
                if (relu) v = fmaxf(v, 0.0f);
                size_t idx = (size_t)row * N + col;
                if (Cf) Cf[idx] = v;
                if (Cb) Cb[idx] = f2b(v);
            }
        }
    }
}

// ---------------- heads via MFMA: [8192,1024] @ WT19^T -> 18 logits + 1 value ----------------
// block = 128 thr (2 waves); wave handles 16 nodes; grid = 8192/32 = 256.
// WT19 staged in LDS [20][1032]; row 19 zeroed (pad lanes read it).
__global__ __launch_bounds__(128) void heads_mfma(
    const ushort* __restrict__ h2b, const ushort* __restrict__ WT19,
    const float* __restrict__ bl, const float* __restrict__ bv,
    float* __restrict__ out_logits, float* __restrict__ out_values)
{
    __shared__ ushort wt[20][1032];   // 41.3 KB

    int t = threadIdx.x;
    for (int idx = t; idx < 19 * 128; idx += 128) {
        int row = idx >> 7, c8 = (idx & 127) * 8;
        *(uint4*)&wt[row][c8] = *(const uint4*)(WT19 + (size_t)row * FOUT + c8);
    }
    {   // zero pad row 19
        uint4 z = {0, 0, 0, 0};
        for (int c8 = t * 8; c8 < FOUT; c8 += 128 * 8) *(uint4*)&wt[19][c8] = z;
    }
    __syncthreads();

    int lane = t & 63, w = t >> 6;
    int l15 = lane & 15, quad = lane >> 4;
    int nb = (blockIdx.x * 2 + w) * 16;           // 16 nodes per wave

    f32x4 acc0 = {}, acc1 = {};
    const ushort* Ab = h2b + (size_t)(nb + l15) * FOUT + quad * 8;
    int r1 = (16 + l15 < 19) ? (16 + l15) : 19;   // clamp pad lanes to zero row

    for (int k0 = 0; k0 < FOUT; k0 += 32) {
        frag8 af = *(const frag8*)(Ab + k0);
        frag8 b0 = *(const frag8*)&wt[l15][k0 + quad * 8];
        frag8 b1 = *(const frag8*)&wt[r1][k0 + quad * 8];
        acc0 = __builtin_amdgcn_mfma_f32_16x16x32_bf16(af, b0, acc0, 0, 0, 0);
        acc1 = __builtin_amdgcn_mfma_f32_16x16x32_bf16(af, b1, acc1, 0, 0, 0);
    }

#pragma unroll
    for (int r = 0; r < 4; ++r) {
        int node = nb + quad * 4 + r;
        out_logits[(size_t)node * NLOG + l15] = acc0[r] + bl[l15];
        if (l15 < 2)       out_logits[(size_t)node * NLOG + 16 + l15] = acc1[r] + bl[16 + l15];
        else if (l15 == 2) out_values[node] = acc1[r] + bv[0];
    }
}

// ---------------- launcher ----------------
extern "C" void kernel_launch(void* const* d_in, const int* in_sizes, int n_in,
                              void* d_out, int out_size, void* d_ws, size_t ws_size,
                              hipStream_t stream) {
    const float* nodes = (const float*)d_in[0];
    const int*   edges = (const int*)d_in[1];
    const float* W0 = (const float*)d_in[2];
    const float* b0 = (const float*)d_in[3];
    const float* W1 = (const float*)d_in[4];
    const float* b1 = (const float*)d_in[5];
    const float* Wl = (const float*)d_in[6];
    const float* bl = (const float*)d_in[7];
    const float* Wv = (const float*)d_in[8];
    const float* bv = (const float*)d_in[9];

    float* out_logits = (float*)d_out;
    float* out_values = out_logits + (size_t)BB * NN * NLOG;

    char* ws = (char*)d_ws;
    // NOTE: offs needs NN+1 ints — its own 36 KB region (round-5 crash was offs[NN]
    // aliasing cursor[0], poisoning CSR slots -> negative index -> memory fault).
    int*    cnt     = (int*)(ws);                     // 32 KB  [0, 32K)
    int*    offs    = (int*)(ws + (32 << 10));        // 36 KB  [32K, 68K)
    int*    cursor  = (int*)(ws + (68 << 10));        // 32 KB  [68K, 100K)
    float*  dinv    = (float*)(ws + (100 << 10));     // 32 KB  [100K, 132K)
    int*    csr_src = (int*)(ws + (132 << 10));       // 256 KB [132K, 388K)
    ushort* W0T     = (ushort*)(ws + (392 << 10));    // 64 KB  [392K, 456K)
    ushort* W1T     = (ushort*)(ws + (456 << 10));    // 512 KB [456K, 968K)
    ushort* WT19    = (ushort*)(ws + (968 << 10));    // 38 KB  [968K, 1006K)
    ushort* xagg_b  = (ushort*)(ws + (1u << 20));     // 2 MB  [N,128]
    ushort* h1b     = (ushort*)(ws + (3u << 20));     // 4 MB  [N,256]
    ushort* hagg_b  = (ushort*)(ws + (7u << 20));     // 4 MB  [N,256]
    ushort* h2b     = (ushort*)(ws + (11u << 20));    // 16 MB [N,1024]
    // total 27 MB

    // weight prep (once per launch)
    w_transpose_cast<<<(FOBS * FH + 255) / 256, 256, 0, stream>>>(W0, W0T, FOBS, FH);
    w_transpose_cast<<<(FH * FOUT + 255) / 256, 256, 0, stream>>>(W1, W1T, FH, FOUT);
    pack_heads_w<<<(19 * FOUT + 255) / 256, 256, 0, stream>>>(Wl, Wv, WT19);

    for (int g = 0; g < BB; ++g) {
        const float* x   = nodes + (size_t)g * NN * FOBS;
        const int*   src = edges + (size_t)g * 2 * EE;
        const int*   dst = src + EE;

        // CSR build
        hipMemsetAsync(cnt, 0, NN * sizeof(int), stream);
        count_kernel<<<(EE + 255) / 256, 256, 0, stream>>>(dst, cnt, EE);
        scan_kernel<<<1, 1024, 0, stream>>>(cnt, offs, cursor, dinv);
        csr_fill<<<(EE + 255) / 256, 256, 0, stream>>>(src, dst, cursor, csr_src, EE);

        // layer 1: h1 = relu((A_hat x) W0 + b0)
        gather_agg_f32<<<NN, FOBS, 0, stream>>>(x, offs, csr_src, dinv, xagg_b, FOBS);
        mfma_gemm<<<dim3(FH / 128, NN / 128), 256, 0, stream>>>(
            xagg_b, W0T, b0, (float*)nullptr, h1b, NN, FH, FOBS, 1);

        // layer 2: h2 = relu((A_hat h1) W1 + b1)
        gather_agg_bf16<<<NN, FH, 0, stream>>>(h1b, offs, csr_src, dinv, hagg_b, FH);
        mfma_gemm<<<dim3(FOUT / 128, NN / 128), 256, 0, stream>>>(
            hagg_b, W1T, b1, (float*)nullptr, h2b, NN, FOUT, FH, 1);

        // heads
        heads_mfma<<<NN / 32, 128, 0, stream>>>(h2b, WT19, bl, bv,
                                                out_logits + (size_t)g * NN * NLOG,
                                                out_values + (size_t)g * NN);
    }
}

// Round 7
// 280.708 us; speedup vs baseline: 6.5471x; 1.3824x over previous
//
#include <hip/hip_runtime.h>
#include <hip/hip_bf16.h>

#define BB   4
#define NN   8192
#define EE   65536
#define FOBS 128
#define FH   256
#define FOUT 1024
#define NLOG 18
#define OFFS_STRIDE (NN + 1)

typedef __attribute__((ext_vector_type(8))) short frag8;
typedef __attribute__((ext_vector_type(4))) float f32x4;

__device__ __forceinline__ ushort f2b(float v) {
    __hip_bfloat16 h = __float2bfloat16(v);
    return *reinterpret_cast<ushort*>(&h);
}
__device__ __forceinline__ float b2f(ushort u) { return __uint_as_float(((uint)u) << 16); }

// ---------------- CSR build (batched over graphs via blockIdx.y) ----------------
__global__ void count_kernel(const int* __restrict__ edges, int* __restrict__ cnt) {
    int g = blockIdx.y;
    int i = blockIdx.x * blockDim.x + threadIdx.x;
    const int* dst = edges + (size_t)g * 2 * EE + EE;
    if (i < EE) atomicAdd(&cnt[(size_t)g * NN + dst[i]], 1);
}

// one block per graph, 1024 threads, 8 elems/thread
__global__ __launch_bounds__(1024) void scan_kernel(const int* __restrict__ cnt_all,
                                                    int* __restrict__ offs_all,
                                                    int* __restrict__ cursor_all,
                                                    float* __restrict__ dinv_all) {
    int g = blockIdx.x;
    const int* cnt = cnt_all + (size_t)g * NN;
    int* offs = offs_all + (size_t)g * OFFS_STRIDE;
    int* cursor = cursor_all + (size_t)g * NN;
    float* dinv = dinv_all + (size_t)g * NN;

    int t = threadIdx.x;
    int base = t * 8;
    int v[8], s = 0;
#pragma unroll
    for (int j = 0; j < 8; ++j) {
        v[j] = cnt[base + j];
        s += v[j];
        dinv[base + j] = rsqrtf((float)v[j] + 1.0f);
    }
    int lane = t & 63, w = t >> 6;
    int pre = s;
#pragma unroll
    for (int d = 1; d < 64; d <<= 1) {
        int x = __shfl_up(pre, d, 64);
        if (lane >= d) pre += x;
    }
    __shared__ int wsum[16];
    if (lane == 63) wsum[w] = pre;
    __syncthreads();
    if (t == 0) {
        int run = 0;
#pragma unroll
        for (int i = 0; i < 16; ++i) { int tmp = wsum[i]; wsum[i] = run; run += tmp; }
    }
    __syncthreads();
    int excl = wsum[w] + (pre - s);
#pragma unroll
    for (int j = 0; j < 8; ++j) {
        offs[base + j] = excl;
        cursor[base + j] = excl;
        excl += v[j];
    }
    if (t == 1023) offs[NN] = excl;
}

__global__ void csr_fill(const int* __restrict__ edges, int* __restrict__ cursor_all,
                         int* __restrict__ csr_all) {
    int g = blockIdx.y;
    int e = blockIdx.x * blockDim.x + threadIdx.x;
    const int* src = edges + (size_t)g * 2 * EE;
    const int* dst = src + EE;
    if (e < EE) {
        int d = dst[e];
        int slot = atomicAdd(&cursor_all[(size_t)g * NN + d], 1);
        csr_all[(size_t)g * EE + slot] = src[e];
    }
}

// ---------------- gather aggregation (no atomics), writes bf16 ----------------
__global__ void gather_agg_f32(const float* __restrict__ x_all, const int* __restrict__ offs_all,
                               const int* __restrict__ csr_all, const float* __restrict__ dinv_all,
                               ushort* __restrict__ agg_all, int F) {
    int g = blockIdx.y, n = blockIdx.x, f = threadIdx.x;
    const float* x = x_all + (size_t)g * NN * F;
    const int* offs = offs_all + (size_t)g * OFFS_STRIDE;
    const int* csr = csr_all + (size_t)g * EE;
    const float* dinv = dinv_all + (size_t)g * NN;

    float wn = dinv[n];
    float acc = wn * wn * x[(size_t)n * F + f];
    int i0 = offs[n], i1 = offs[n + 1];
    for (int i = i0; i < i1; ++i) {
        int s = csr[i];
        acc += dinv[s] * wn * x[(size_t)s * F + f];
    }
    agg_all[((size_t)g * NN + n) * F + f] = f2b(acc);
}

__global__ void gather_agg_bf16(const ushort* __restrict__ xb_all, const int* __restrict__ offs_all,
                                const int* __restrict__ csr_all, const float* __restrict__ dinv_all,
                                ushort* __restrict__ agg_all, int F) {
    int g = blockIdx.y, n = blockIdx.x, f = threadIdx.x;
    const ushort* xb = xb_all + (size_t)g * NN * F;
    const int* offs = offs_all + (size_t)g * OFFS_STRIDE;
    const int* csr = csr_all + (size_t)g * EE;
    const float* dinv = dinv_all + (size_t)g * NN;

    float wn = dinv[n];
    float acc = wn * wn * b2f(xb[(size_t)n * F + f]);
    int i0 = offs[n], i1 = offs[n + 1];
    for (int i = i0; i < i1; ++i) {
        int s = csr[i];
        acc += dinv[s] * wn * b2f(xb[(size_t)s * F + f]);
    }
    agg_all[((size_t)g * NN + n) * F + f] = f2b(acc);
}

// ---------------- weight prep ----------------
__global__ void w_transpose_cast(const float* __restrict__ W, ushort* __restrict__ WT,
                                 int K, int N) {
    int i = blockIdx.x * blockDim.x + threadIdx.x;
    if (i < K * N) {
        int n = i / K, k = i - n * K;
        WT[i] = f2b(W[(size_t)k * N + n]);
    }
}

__global__ void pack_heads_w(const float* __restrict__ Wl, const float* __restrict__ Wv,
                             ushort* __restrict__ WT19) {
    int i = blockIdx.x * blockDim.x + threadIdx.x;
    if (i < 19 * FOUT) {
        int o = i >> 10, k = i & (FOUT - 1);
        WT19[i] = f2b((o < NLOG) ? Wl[(size_t)k * NLOG + o] : Wv[k]);
    }
}

// ---------------- MFMA GEMM (batched via blockIdx.z): C = relu(A @ BT^T + bias) ----------------
__global__ __launch_bounds__(256) void mfma_gemm(
    const ushort* __restrict__ A_all, const ushort* __restrict__ BT,
    const float* __restrict__ bias, ushort* __restrict__ C_all,
    int M, int N, int K, int relu)
{
    __shared__ ushort As[128][72];
    __shared__ ushort Bs[128][72];

    int g = blockIdx.z;
    const ushort* A = A_all + (size_t)g * M * K;
    ushort* C = C_all + (size_t)g * M * N;

    int t = threadIdx.x;
    int bn = blockIdx.x, bm = blockIdx.y;
    int lane = t & 63, w = t >> 6;
    int wm = w >> 1, wn = w & 1;
    int l15 = lane & 15, quad = lane >> 4;

    f32x4 acc[4][4] = {};

    int srow = t >> 3, scol = (t & 7) * 8;
    const ushort* Abase = A + (size_t)(bm * 128) * K;
    const ushort* Bbase = BT + (size_t)(bn * 128) * K;

    for (int k0 = 0; k0 < K; k0 += 64) {
#pragma unroll
        for (int i = 0; i < 4; ++i) {
            int row = srow + 32 * i;
            *(uint4*)&As[row][scol] = *(const uint4*)(Abase + (size_t)row * K + k0 + scol);
        }
#pragma unroll
        for (int i = 0; i < 4; ++i) {
            int row = srow + 32 * i;
            *(uint4*)&Bs[row][scol] = *(const uint4*)(Bbase + (size_t)row * K + k0 + scol);
        }
        __syncthreads();
#pragma unroll
        for (int kk = 0; kk < 64; kk += 32) {
            frag8 af[4], bf[4];
#pragma unroll
            for (int i = 0; i < 4; ++i)
                af[i] = *(const frag8*)&As[wm * 64 + i * 16 + l15][kk + quad * 8];
#pragma unroll
            for (int j = 0; j < 4; ++j)
                bf[j] = *(const frag8*)&Bs[wn * 64 + j * 16 + l15][kk + quad * 8];
#pragma unroll
            for (int i = 0; i < 4; ++i)
#pragma unroll
                for (int j = 0; j < 4; ++j)
                    acc[i][j] = __builtin_amdgcn_mfma_f32_16x16x32_bf16(af[i], bf[j], acc[i][j], 0, 0, 0);
        }
        __syncthreads();
    }

#pragma unroll
    for (int i = 0; i < 4; ++i) {
#pragma unroll
        for (int j = 0; j < 4; ++j) {
            int col = bn * 128 + wn * 64 + j * 16 + l15;
            float bcol = bias[col];
#pragma unroll
            for (int r = 0; r < 4; ++r) {
                int row = bm * 128 + wm * 64 + i * 16 + quad * 4 + r;
                float v = acc[i][j][r] + bcol;
                if (relu) v = fmaxf(v, 0.0f);
                C[(size_t)row * N + col] = f2b(v);
            }
        }
    }
}

// ---------------- heads via MFMA (batched via blockIdx.y) ----------------
__global__ __launch_bounds__(128) void heads_mfma(
    const ushort* __restrict__ h2_all, const ushort* __restrict__ WT19,
    const float* __restrict__ bl, const float* __restrict__ bv,
    float* __restrict__ out_logits_all, float* __restrict__ out_values_all)
{
    __shared__ ushort wt[20][1032];   // 41.3 KB

    int g = blockIdx.y;
    const ushort* h2b = h2_all + (size_t)g * NN * FOUT;
    float* out_logits = out_logits_all + (size_t)g * NN * NLOG;
    float* out_values = out_values_all + (size_t)g * NN;

    int t = threadIdx.x;
    for (int idx = t; idx < 19 * 128; idx += 128) {
        int row = idx >> 7, c8 = (idx & 127) * 8;
        *(uint4*)&wt[row][c8] = *(const uint4*)(WT19 + (size_t)row * FOUT + c8);
    }
    {
        uint4 z = {0, 0, 0, 0};
        for (int c8 = t * 8; c8 < FOUT; c8 += 128 * 8) *(uint4*)&wt[19][c8] = z;
    }
    __syncthreads();

    int lane = t & 63, w = t >> 6;
    int l15 = lane & 15, quad = lane >> 4;
    int nb = (blockIdx.x * 2 + w) * 16;

    f32x4 acc0 = {}, acc1 = {};
    const ushort* Ab = h2b + (size_t)(nb + l15) * FOUT + quad * 8;
    int r1 = (16 + l15 < 19) ? (16 + l15) : 19;

    for (int k0 = 0; k0 < FOUT; k0 += 32) {
        frag8 af = *(const frag8*)(Ab + k0);
        frag8 b0 = *(const frag8*)&wt[l15][k0 + quad * 8];
        frag8 b1 = *(const frag8*)&wt[r1][k0 + quad * 8];
        acc0 = __builtin_amdgcn_mfma_f32_16x16x32_bf16(af, b0, acc0, 0, 0, 0);
        acc1 = __builtin_amdgcn_mfma_f32_16x16x32_bf16(af, b1, acc1, 0, 0, 0);
    }

#pragma unroll
    for (int r = 0; r < 4; ++r) {
        int node = nb + quad * 4 + r;
        out_logits[(size_t)node * NLOG + l15] = acc0[r] + bl[l15];
        if (l15 < 2)       out_logits[(size_t)node * NLOG + 16 + l15] = acc1[r] + bl[16 + l15];
        else if (l15 == 2) out_values[node] = acc1[r] + bv[0];
    }
}

// ---------------- launcher ----------------
extern "C" void kernel_launch(void* const* d_in, const int* in_sizes, int n_in,
                              void* d_out, int out_size, void* d_ws, size_t ws_size,
                              hipStream_t stream) {
    const float* nodes = (const float*)d_in[0];
    const int*   edges = (const int*)d_in[1];
    const float* W0 = (const float*)d_in[2];
    const float* b0 = (const float*)d_in[3];
    const float* W1 = (const float*)d_in[4];
    const float* b1 = (const float*)d_in[5];
    const float* Wl = (const float*)d_in[6];
    const float* bl = (const float*)d_in[7];
    const float* Wv = (const float*)d_in[8];
    const float* bv = (const float*)d_in[9];

    float* out_logits = (float*)d_out;
    float* out_values = out_logits + (size_t)BB * NN * NLOG;

    char* ws = (char*)d_ws;
    // batched (x4) buffers
    int*    cnt     = (int*)(ws);                     // 128 KB [0, 128K)
    int*    offs    = (int*)(ws + (128 << 10));       // 132 KB [128K, 260K)  stride NN+1
    int*    cursor  = (int*)(ws + (260 << 10));       // 128 KB [260K, 388K)
    float*  dinv    = (float*)(ws + (388 << 10));     // 128 KB [388K, 516K)
    int*    csr_src = (int*)(ws + (516 << 10));       // 1 MB   [516K, 1540K)
    ushort* W0T     = (ushort*)(ws + (1540 << 10));   // 64 KB
    ushort* W1T     = (ushort*)(ws + (1604 << 10));   // 512 KB
    ushort* WT19    = (ushort*)(ws + (2116 << 10));   // 38 KB   (ends 2154K)
    ushort* xagg_b  = (ushort*)(ws + (4u << 20));     // 8 MB   [4M, 12M)   [B,N,128]
    ushort* h1b     = (ushort*)(ws + (12u << 20));    // 16 MB  [12M, 28M)  [B,N,256]
    ushort* hagg_b  = (ushort*)(ws + (28u << 20));    // 16 MB  [28M, 44M)  [B,N,256]
    ushort* h2b     = (ushort*)(ws + (44u << 20));    // 64 MB  [44M, 108M) [B,N,1024]
    // total 108 MB

    // weight prep
    w_transpose_cast<<<(FOBS * FH + 255) / 256, 256, 0, stream>>>(W0, W0T, FOBS, FH);
    w_transpose_cast<<<(FH * FOUT + 255) / 256, 256, 0, stream>>>(W1, W1T, FH, FOUT);
    pack_heads_w<<<(19 * FOUT + 255) / 256, 256, 0, stream>>>(Wl, Wv, WT19);

    // CSR build (all graphs)
    hipMemsetAsync(cnt, 0, (size_t)BB * NN * sizeof(int), stream);
    count_kernel<<<dim3(EE / 256, BB), 256, 0, stream>>>(edges, cnt);
    scan_kernel<<<BB, 1024, 0, stream>>>(cnt, offs, cursor, dinv);
    csr_fill<<<dim3(EE / 256, BB), 256, 0, stream>>>(edges, cursor, csr_src);

    // layer 1: h1 = relu((A_hat x) W0 + b0)
    gather_agg_f32<<<dim3(NN, BB), FOBS, 0, stream>>>(nodes, offs, csr_src, dinv, xagg_b, FOBS);
    mfma_gemm<<<dim3(FH / 128, NN / 128, BB), 256, 0, stream>>>(
        xagg_b, W0T, b0, h1b, NN, FH, FOBS, 1);

    // layer 2: h2 = relu((A_hat h1) W1 + b1)
    gather_agg_bf16<<<dim3(NN, BB), FH, 0, stream>>>(h1b, offs, csr_src, dinv, hagg_b, FH);
    mfma_gemm<<<dim3(FOUT / 128, NN / 128, BB), 256, 0, stream>>>(
        hagg_b, W1T, b1, h2b, NN, FOUT, FH, 1);

    // heads
    heads_mfma<<<dim3(NN / 32, BB), 128, 0, stream>>>(h2b, WT19, bl, bv, out_logits, out_values);
}

// Round 8
// 233.001 us; speedup vs baseline: 7.8876x; 1.2048x over previous
//
#include <hip/hip_runtime.h>
#include <hip/hip_bf16.h>

#define BB   4
#define NN   8192
#define EE   65536
#define FOBS 128
#define FH   256
#define FOUT 1024
#define NLOG 18
#define OFFS_STRIDE (NN + 1)

typedef __attribute__((ext_vector_type(8))) short frag8;
typedef __attribute__((ext_vector_type(4))) float f32x4;

__device__ __forceinline__ ushort f2b(float v) {
    __hip_bfloat16 h = __float2bfloat16(v);
    return *reinterpret_cast<ushort*>(&h);
}
__device__ __forceinline__ float b2f(ushort u) { return __uint_as_float(((uint)u) << 16); }
__device__ __forceinline__ float blo(uint u) { return __uint_as_float(u << 16); }
__device__ __forceinline__ float bhi(uint u) { return __uint_as_float(u & 0xffff0000u); }

// ---------------- CSR build (batched over graphs via blockIdx.y) ----------------
__global__ void count_kernel(const int* __restrict__ edges, int* __restrict__ cnt) {
    int g = blockIdx.y;
    int i = blockIdx.x * blockDim.x + threadIdx.x;
    const int* dst = edges + (size_t)g * 2 * EE + EE;
    if (i < EE) atomicAdd(&cnt[(size_t)g * NN + dst[i]], 1);
}

__global__ __launch_bounds__(1024) void scan_kernel(const int* __restrict__ cnt_all,
                                                    int* __restrict__ offs_all,
                                                    int* __restrict__ cursor_all,
                                                    float* __restrict__ dinv_all) {
    int g = blockIdx.x;
    const int* cnt = cnt_all + (size_t)g * NN;
    int* offs = offs_all + (size_t)g * OFFS_STRIDE;
    int* cursor = cursor_all + (size_t)g * NN;
    float* dinv = dinv_all + (size_t)g * NN;

    int t = threadIdx.x;
    int base = t * 8;
    int v[8], s = 0;
#pragma unroll
    for (int j = 0; j < 8; ++j) {
        v[j] = cnt[base + j];
        s += v[j];
        dinv[base + j] = rsqrtf((float)v[j] + 1.0f);
    }
    int lane = t & 63, w = t >> 6;
    int pre = s;
#pragma unroll
    for (int d = 1; d < 64; d <<= 1) {
        int x = __shfl_up(pre, d, 64);
        if (lane >= d) pre += x;
    }
    __shared__ int wsum[16];
    if (lane == 63) wsum[w] = pre;
    __syncthreads();
    if (t == 0) {
        int run = 0;
#pragma unroll
        for (int i = 0; i < 16; ++i) { int tmp = wsum[i]; wsum[i] = run; run += tmp; }
    }
    __syncthreads();
    int excl = wsum[w] + (pre - s);
#pragma unroll
    for (int j = 0; j < 8; ++j) {
        offs[base + j] = excl;
        cursor[base + j] = excl;
        excl += v[j];
    }
    if (t == 1023) offs[NN] = excl;
}

__global__ void csr_fill(const int* __restrict__ edges, int* __restrict__ cursor_all,
                         int* __restrict__ csr_all) {
    int g = blockIdx.y;
    int e = blockIdx.x * blockDim.x + threadIdx.x;
    const int* src = edges + (size_t)g * 2 * EE;
    const int* dst = src + EE;
    if (e < EE) {
        int d = dst[e];
        int slot = atomicAdd(&cursor_all[(size_t)g * NN + d], 1);
        csr_all[(size_t)g * EE + slot] = src[e];
    }
}

// ---------------- gather aggregation: wave-per-node, 8B/lane, 4-deep MLP ----------------
// layer 1: x f32 [N,128]; lane holds 2 features (float2 = 8B). Output bf16 packed.
__global__ __launch_bounds__(256) void gather_agg_f32(
    const float* __restrict__ x_all, const int* __restrict__ offs_all,
    const int* __restrict__ csr_all, const float* __restrict__ dinv_all,
    uint* __restrict__ agg_all)   // agg as packed bf16 pairs [B*N, 64]
{
    int g = blockIdx.y;
    int wv = threadIdx.x >> 6, lane = threadIdx.x & 63;
    int n = blockIdx.x * 4 + wv;
    const float2* x = (const float2*)(x_all + (size_t)g * NN * FOBS);
    const int* offs = offs_all + (size_t)g * OFFS_STRIDE;
    const int* csr = csr_all + (size_t)g * EE;
    const float* dinv = dinv_all + (size_t)g * NN;

    float wn = dinv[n];
    float2 self = x[(size_t)n * 64 + lane];
    float ax = wn * wn * self.x, ay = wn * wn * self.y;

    int i0 = offs[n], i1 = offs[n + 1];
    int i = i0;
    for (; i + 4 <= i1; i += 4) {
        int s0 = csr[i], s1 = csr[i + 1], s2 = csr[i + 2], s3 = csr[i + 3];
        float w0 = dinv[s0] * wn, w1 = dinv[s1] * wn, w2 = dinv[s2] * wn, w3 = dinv[s3] * wn;
        float2 r0 = x[(size_t)s0 * 64 + lane];
        float2 r1 = x[(size_t)s1 * 64 + lane];
        float2 r2 = x[(size_t)s2 * 64 + lane];
        float2 r3 = x[(size_t)s3 * 64 + lane];
        ax += w0 * r0.x + w1 * r1.x + w2 * r2.x + w3 * r3.x;
        ay += w0 * r0.y + w1 * r1.y + w2 * r2.y + w3 * r3.y;
    }
    for (; i < i1; ++i) {
        int s = csr[i];
        float w = dinv[s] * wn;
        float2 r = x[(size_t)s * 64 + lane];
        ax += w * r.x; ay += w * r.y;
    }
    agg_all[((size_t)g * NN + n) * 64 + lane] = (uint)f2b(ax) | ((uint)f2b(ay) << 16);
}

// layer 2: xb bf16 [N,256]; lane holds 4 features (uint2 = 8B).
__global__ __launch_bounds__(256) void gather_agg_bf16(
    const uint2* __restrict__ xb_all, const int* __restrict__ offs_all,
    const int* __restrict__ csr_all, const float* __restrict__ dinv_all,
    uint2* __restrict__ agg_all)
{
    int g = blockIdx.y;
    int wv = threadIdx.x >> 6, lane = threadIdx.x & 63;
    int n = blockIdx.x * 4 + wv;
    const uint2* xb = xb_all + (size_t)g * NN * 64;   // 64 uint2 per row of 256 bf16
    const int* offs = offs_all + (size_t)g * OFFS_STRIDE;
    const int* csr = csr_all + (size_t)g * EE;
    const float* dinv = dinv_all + (size_t)g * NN;

    float wn = dinv[n];
    uint2 u = xb[(size_t)n * 64 + lane];
    float w2 = wn * wn;
    float a0 = w2 * blo(u.x), a1 = w2 * bhi(u.x), a2 = w2 * blo(u.y), a3 = w2 * bhi(u.y);

    int i0 = offs[n], i1 = offs[n + 1];
    int i = i0;
    for (; i + 4 <= i1; i += 4) {
        int s0 = csr[i], s1 = csr[i + 1], s2 = csr[i + 2], s3 = csr[i + 3];
        float w0 = dinv[s0] * wn, w1 = dinv[s1] * wn, ww2 = dinv[s2] * wn, w3 = dinv[s3] * wn;
        uint2 r0 = xb[(size_t)s0 * 64 + lane];
        uint2 r1 = xb[(size_t)s1 * 64 + lane];
        uint2 r2 = xb[(size_t)s2 * 64 + lane];
        uint2 r3 = xb[(size_t)s3 * 64 + lane];
        a0 += w0 * blo(r0.x) + w1 * blo(r1.x) + ww2 * blo(r2.x) + w3 * blo(r3.x);
        a1 += w0 * bhi(r0.x) + w1 * bhi(r1.x) + ww2 * bhi(r2.x) + w3 * bhi(r3.x);
        a2 += w0 * blo(r0.y) + w1 * blo(r1.y) + ww2 * blo(r2.y) + w3 * blo(r3.y);
        a3 += w0 * bhi(r0.y) + w1 * bhi(r1.y) + ww2 * bhi(r2.y) + w3 * bhi(r3.y);
    }
    for (; i < i1; ++i) {
        int s = csr[i];
        float w = dinv[s] * wn;
        uint2 r = xb[(size_t)s * 64 + lane];
        a0 += w * blo(r.x); a1 += w * bhi(r.x);
        a2 += w * blo(r.y); a3 += w * bhi(r.y);
    }
    uint2 o;
    o.x = (uint)f2b(a0) | ((uint)f2b(a1) << 16);
    o.y = (uint)f2b(a2) | ((uint)f2b(a3) << 16);
    agg_all[((size_t)g * NN + n) * 64 + lane] = o;
}

// ---------------- weight prep ----------------
__global__ void w_transpose_cast(const float* __restrict__ W, ushort* __restrict__ WT,
                                 int K, int N) {
    int i = blockIdx.x * blockDim.x + threadIdx.x;
    if (i < K * N) {
        int n = i / K, k = i - n * K;
        WT[i] = f2b(W[(size_t)k * N + n]);
    }
}

__global__ void pack_heads_w(const float* __restrict__ Wl, const float* __restrict__ Wv,
                             ushort* __restrict__ WT19) {
    int i = blockIdx.x * blockDim.x + threadIdx.x;
    if (i < 19 * FOUT) {
        int o = i >> 10, k = i & (FOUT - 1);
        WT19[i] = f2b((o < NLOG) ? Wl[(size_t)k * NLOG + o] : Wv[k]);
    }
}

// ---------------- MFMA GEMM (batched via blockIdx.z): C = relu(A @ BT^T + bias) ----------------
__global__ __launch_bounds__(256) void mfma_gemm(
    const ushort* __restrict__ A_all, const ushort* __restrict__ BT,
    const float* __restrict__ bias, ushort* __restrict__ C_all,
    int M, int N, int K, int relu)
{
    __shared__ ushort As[128][72];
    __shared__ ushort Bs[128][72];

    int g = blockIdx.z;
    const ushort* A = A_all + (size_t)g * M * K;
    ushort* C = C_all + (size_t)g * M * N;

    int t = threadIdx.x;
    int bn = blockIdx.x, bm = blockIdx.y;
    int lane = t & 63, w = t >> 6;
    int wm = w >> 1, wn = w & 1;
    int l15 = lane & 15, quad = lane >> 4;

    f32x4 acc[4][4] = {};

    int srow = t >> 3, scol = (t & 7) * 8;
    const ushort* Abase = A + (size_t)(bm * 128) * K;
    const ushort* Bbase = BT + (size_t)(bn * 128) * K;

    for (int k0 = 0; k0 < K; k0 += 64) {
#pragma unroll
        for (int i = 0; i < 4; ++i) {
            int row = srow + 32 * i;
            *(uint4*)&As[row][scol] = *(const uint4*)(Abase + (size_t)row * K + k0 + scol);
        }
#pragma unroll
        for (int i = 0; i < 4; ++i) {
            int row = srow + 32 * i;
            *(uint4*)&Bs[row][scol] = *(const uint4*)(Bbase + (size_t)row * K + k0 + scol);
        }
        __syncthreads();
#pragma unroll
        for (int kk = 0; kk < 64; kk += 32) {
            frag8 af[4], bf[4];
#pragma unroll
            for (int i = 0; i < 4; ++i)
                af[i] = *(const frag8*)&As[wm * 64 + i * 16 + l15][kk + quad * 8];
#pragma unroll
            for (int j = 0; j < 4; ++j)
                bf[j] = *(const frag8*)&Bs[wn * 64 + j * 16 + l15][kk + quad * 8];
#pragma unroll
            for (int i = 0; i < 4; ++i)
#pragma unroll
                for (int j = 0; j < 4; ++j)
                    acc[i][j] = __builtin_amdgcn_mfma_f32_16x16x32_bf16(af[i], bf[j], acc[i][j], 0, 0, 0);
        }
        __syncthreads();
    }

#pragma unroll
    for (int i = 0; i < 4; ++i) {
#pragma unroll
        for (int j = 0; j < 4; ++j) {
            int col = bn * 128 + wn * 64 + j * 16 + l15;
            float bcol = bias[col];
#pragma unroll
            for (int r = 0; r < 4; ++r) {
                int row = bm * 128 + wm * 64 + i * 16 + quad * 4 + r;
                float v = acc[i][j][r] + bcol;
                if (relu) v = fmaxf(v, 0.0f);
                C[(size_t)row * N + col] = f2b(v);
            }
        }
    }
}

// ---------------- heads via MFMA (batched via blockIdx.y) ----------------
__global__ __launch_bounds__(128) void heads_mfma(
    const ushort* __restrict__ h2_all, const ushort* __restrict__ WT19,
    const float* __restrict__ bl, const float* __restrict__ bv,
    float* __restrict__ out_logits_all, float* __restrict__ out_values_all)
{
    __shared__ ushort wt[20][1032];   // 41.3 KB

    int g = blockIdx.y;
    const ushort* h2b = h2_all + (size_t)g * NN * FOUT;
    float* out_logits = out_logits_all + (size_t)g * NN * NLOG;
    float* out_values = out_values_all + (size_t)g * NN;

    int t = threadIdx.x;
    for (int idx = t; idx < 19 * 128; idx += 128) {
        int row = idx >> 7, c8 = (idx & 127) * 8;
        *(uint4*)&wt[row][c8] = *(const uint4*)(WT19 + (size_t)row * FOUT + c8);
    }
    {
        uint4 z = {0, 0, 0, 0};
        for (int c8 = t * 8; c8 < FOUT; c8 += 128 * 8) *(uint4*)&wt[19][c8] = z;
    }
    __syncthreads();

    int lane = t & 63, w = t >> 6;
    int l15 = lane & 15, quad = lane >> 4;
    int nb = (blockIdx.x * 2 + w) * 16;

    f32x4 acc0 = {}, acc1 = {};
    const ushort* Ab = h2b + (size_t)(nb + l15) * FOUT + quad * 8;
    int r1 = (16 + l15 < 19) ? (16 + l15) : 19;

    for (int k0 = 0; k0 < FOUT; k0 += 32) {
        frag8 af = *(const frag8*)(Ab + k0);
        frag8 b0 = *(const frag8*)&wt[l15][k0 + quad * 8];
        frag8 b1 = *(const frag8*)&wt[r1][k0 + quad * 8];
        acc0 = __builtin_amdgcn_mfma_f32_16x16x32_bf16(af, b0, acc0, 0, 0, 0);
        acc1 = __builtin_amdgcn_mfma_f32_16x16x32_bf16(af, b1, acc1, 0, 0, 0);
    }

#pragma unroll
    for (int r = 0; r < 4; ++r) {
        int node = nb + quad * 4 + r;
        out_logits[(size_t)node * NLOG + l15] = acc0[r] + bl[l15];
        if (l15 < 2)       out_logits[(size_t)node * NLOG + 16 + l15] = acc1[r] + bl[16 + l15];
        else if (l15 == 2) out_values[node] = acc1[r] + bv[0];
    }
}

// ---------------- launcher ----------------
extern "C" void kernel_launch(void* const* d_in, const int* in_sizes, int n_in,
                              void* d_out, int out_size, void* d_ws, size_t ws_size,
                              hipStream_t stream) {
    const float* nodes = (const float*)d_in[0];
    const int*   edges = (const int*)d_in[1];
    const float* W0 = (const float*)d_in[2];
    const float* b0 = (const float*)d_in[3];
    const float* W1 = (const float*)d_in[4];
    const float* b1 = (const float*)d_in[5];
    const float* Wl = (const float*)d_in[6];
    const float* bl = (const float*)d_in[7];
    const float* Wv = (const float*)d_in[8];
    const float* bv = (const float*)d_in[9];

    float* out_logits = (float*)d_out;
    float* out_values = out_logits + (size_t)BB * NN * NLOG;

    char* ws = (char*)d_ws;
    int*    cnt     = (int*)(ws);                     // 128 KB [0, 128K)
    int*    offs    = (int*)(ws + (128 << 10));       // 132 KB [128K, 260K)  stride NN+1
    int*    cursor  = (int*)(ws + (260 << 10));       // 128 KB [260K, 388K)
    float*  dinv    = (float*)(ws + (388 << 10));     // 128 KB [388K, 516K)
    int*    csr_src = (int*)(ws + (516 << 10));       // 1 MB   [516K, 1540K)
    ushort* W0T     = (ushort*)(ws + (1540 << 10));   // 64 KB
    ushort* W1T     = (ushort*)(ws + (1604 << 10));   // 512 KB
    ushort* WT19    = (ushort*)(ws + (2116 << 10));   // 38 KB   (ends 2154K)
    ushort* xagg_b  = (ushort*)(ws + (4u << 20));     // 8 MB   [4M, 12M)   [B,N,128]
    ushort* h1b     = (ushort*)(ws + (12u << 20));    // 16 MB  [12M, 28M)  [B,N,256]
    ushort* hagg_b  = (ushort*)(ws + (28u << 20));    // 16 MB  [28M, 44M)  [B,N,256]
    ushort* h2b     = (ushort*)(ws + (44u << 20));    // 64 MB  [44M, 108M) [B,N,1024]
    // total 108 MB

    // weight prep
    w_transpose_cast<<<(FOBS * FH + 255) / 256, 256, 0, stream>>>(W0, W0T, FOBS, FH);
    w_transpose_cast<<<(FH * FOUT + 255) / 256, 256, 0, stream>>>(W1, W1T, FH, FOUT);
    pack_heads_w<<<(19 * FOUT + 255) / 256, 256, 0, stream>>>(Wl, Wv, WT19);

    // CSR build (all graphs)
    hipMemsetAsync(cnt, 0, (size_t)BB * NN * sizeof(int), stream);
    count_kernel<<<dim3(EE / 256, BB), 256, 0, stream>>>(edges, cnt);
    scan_kernel<<<BB, 1024, 0, stream>>>(cnt, offs, cursor, dinv);
    csr_fill<<<dim3(EE / 256, BB), 256, 0, stream>>>(edges, cursor, csr_src);

    // layer 1: h1 = relu((A_hat x) W0 + b0)
    gather_agg_f32<<<dim3(NN / 4, BB), 256, 0, stream>>>(nodes, offs, csr_src, dinv,
                                                         (uint*)xagg_b);
    mfma_gemm<<<dim3(FH / 128, NN / 128, BB), 256, 0, stream>>>(
        xagg_b, W0T, b0, h1b, NN, FH, FOBS, 1);

    // layer 2: h2 = relu((A_hat h1) W1 + b1)
    gather_agg_bf16<<<dim3(NN / 4, BB), 256, 0, stream>>>((const uint2*)h1b, offs, csr_src,
                                                          dinv, (uint2*)hagg_b);
    mfma_gemm<<<dim3(FOUT / 128, NN / 128, BB), 256, 0, stream>>>(
        hagg_b, W1T, b1, h2b, NN, FOUT, FH, 1);

    // heads
    heads_mfma<<<dim3(NN / 32, BB), 128, 0, stream>>>(h2b, WT19, bl, bv, out_logits, out_values);
}

// Round 9
// 205.146 us; speedup vs baseline: 8.9586x; 1.1358x over previous
//
#include <hip/hip_runtime.h>
#include <hip/hip_bf16.h>

#define BB   4
#define NN   8192
#define EE   65536
#define FOBS 128
#define FH   256
#define FOUT 1024
#define NLOG 18
#define OFFS_STRIDE (NN + 1)
#define P20  20

typedef __attribute__((ext_vector_type(8))) short frag8;
typedef __attribute__((ext_vector_type(4))) float f32x4;

__device__ __forceinline__ ushort f2b(float v) {
    __hip_bfloat16 h = __float2bfloat16(v);
    return *reinterpret_cast<ushort*>(&h);
}
__device__ __forceinline__ float b2f(ushort u) { return __uint_as_float(((uint)u) << 16); }
__device__ __forceinline__ float blo(uint u) { return __uint_as_float(u << 16); }
__device__ __forceinline__ float bhi(uint u) { return __uint_as_float(u & 0xffff0000u); }

// ---------------- CSR build (batched over graphs via blockIdx.y) ----------------
__global__ void count_kernel(const int* __restrict__ edges, int* __restrict__ cnt) {
    int g = blockIdx.y;
    int i = blockIdx.x * blockDim.x + threadIdx.x;
    const int* dst = edges + (size_t)g * 2 * EE + EE;
    if (i < EE) atomicAdd(&cnt[(size_t)g * NN + dst[i]], 1);
}

__global__ __launch_bounds__(1024) void scan_kernel(const int* __restrict__ cnt_all,
                                                    int* __restrict__ offs_all,
                                                    int* __restrict__ cursor_all,
                                                    float* __restrict__ dinv_all) {
    int g = blockIdx.x;
    const int* cnt = cnt_all + (size_t)g * NN;
    int* offs = offs_all + (size_t)g * OFFS_STRIDE;
    int* cursor = cursor_all + (size_t)g * NN;
    float* dinv = dinv_all + (size_t)g * NN;

    int t = threadIdx.x;
    int base = t * 8;
    int v[8], s = 0;
#pragma unroll
    for (int j = 0; j < 8; ++j) {
        v[j] = cnt[base + j];
        s += v[j];
        dinv[base + j] = rsqrtf((float)v[j] + 1.0f);
    }
    int lane = t & 63, w = t >> 6;
    int pre = s;
#pragma unroll
    for (int d = 1; d < 64; d <<= 1) {
        int x = __shfl_up(pre, d, 64);
        if (lane >= d) pre += x;
    }
    __shared__ int wsum[16];
    if (lane == 63) wsum[w] = pre;
    __syncthreads();
    if (t == 0) {
        int run = 0;
#pragma unroll
        for (int i = 0; i < 16; ++i) { int tmp = wsum[i]; wsum[i] = run; run += tmp; }
    }
    __syncthreads();
    int excl = wsum[w] + (pre - s);
#pragma unroll
    for (int j = 0; j < 8; ++j) {
        offs[base + j] = excl;
        cursor[base + j] = excl;
        excl += v[j];
    }
    if (t == 1023) offs[NN] = excl;
}

__global__ void csr_fill(const int* __restrict__ edges, int* __restrict__ cursor_all,
                         int* __restrict__ csr_all) {
    int g = blockIdx.y;
    int e = blockIdx.x * blockDim.x + threadIdx.x;
    const int* src = edges + (size_t)g * 2 * EE;
    const int* dst = src + EE;
    if (e < EE) {
        int d = dst[e];
        int slot = atomicAdd(&cursor_all[(size_t)g * NN + d], 1);
        csr_all[(size_t)g * EE + slot] = src[e];
    }
}

// ---------------- gather aggregation: wave-per-node, 8B/lane, 4-deep MLP ----------------
__global__ __launch_bounds__(256) void gather_agg_f32(
    const float* __restrict__ x_all, const int* __restrict__ offs_all,
    const int* __restrict__ csr_all, const float* __restrict__ dinv_all,
    uint* __restrict__ agg_all)
{
    int g = blockIdx.y;
    int wv = threadIdx.x >> 6, lane = threadIdx.x & 63;
    int n = blockIdx.x * 4 + wv;
    const float2* x = (const float2*)(x_all + (size_t)g * NN * FOBS);
    const int* offs = offs_all + (size_t)g * OFFS_STRIDE;
    const int* csr = csr_all + (size_t)g * EE;
    const float* dinv = dinv_all + (size_t)g * NN;

    float wn = dinv[n];
    float2 self = x[(size_t)n * 64 + lane];
    float ax = wn * wn * self.x, ay = wn * wn * self.y;

    int i0 = offs[n], i1 = offs[n + 1];
    int i = i0;
    for (; i + 4 <= i1; i += 4) {
        int s0 = csr[i], s1 = csr[i + 1], s2 = csr[i + 2], s3 = csr[i + 3];
        float w0 = dinv[s0] * wn, w1 = dinv[s1] * wn, w2 = dinv[s2] * wn, w3 = dinv[s3] * wn;
        float2 r0 = x[(size_t)s0 * 64 + lane];
        float2 r1 = x[(size_t)s1 * 64 + lane];
        float2 r2 = x[(size_t)s2 * 64 + lane];
        float2 r3 = x[(size_t)s3 * 64 + lane];
        ax += w0 * r0.x + w1 * r1.x + w2 * r2.x + w3 * r3.x;
        ay += w0 * r0.y + w1 * r1.y + w2 * r2.y + w3 * r3.y;
    }
    for (; i < i1; ++i) {
        int s = csr[i];
        float w = dinv[s] * wn;
        float2 r = x[(size_t)s * 64 + lane];
        ax += w * r.x; ay += w * r.y;
    }
    agg_all[((size_t)g * NN + n) * 64 + lane] = (uint)f2b(ax) | ((uint)f2b(ay) << 16);
}

__global__ __launch_bounds__(256) void gather_agg_bf16(
    const uint2* __restrict__ xb_all, const int* __restrict__ offs_all,
    const int* __restrict__ csr_all, const float* __restrict__ dinv_all,
    uint2* __restrict__ agg_all)
{
    int g = blockIdx.y;
    int wv = threadIdx.x >> 6, lane = threadIdx.x & 63;
    int n = blockIdx.x * 4 + wv;
    const uint2* xb = xb_all + (size_t)g * NN * 64;
    const int* offs = offs_all + (size_t)g * OFFS_STRIDE;
    const int* csr = csr_all + (size_t)g * EE;
    const float* dinv = dinv_all + (size_t)g * NN;

    float wn = dinv[n];
    uint2 u = xb[(size_t)n * 64 + lane];
    float w2 = wn * wn;
    float a0 = w2 * blo(u.x), a1 = w2 * bhi(u.x), a2 = w2 * blo(u.y), a3 = w2 * bhi(u.y);

    int i0 = offs[n], i1 = offs[n + 1];
    int i = i0;
    for (; i + 4 <= i1; i += 4) {
        int s0 = csr[i], s1 = csr[i + 1], s2 = csr[i + 2], s3 = csr[i + 3];
        float w0 = dinv[s0] * wn, w1 = dinv[s1] * wn, ww2 = dinv[s2] * wn, w3 = dinv[s3] * wn;
        uint2 r0 = xb[(size_t)s0 * 64 + lane];
        uint2 r1 = xb[(size_t)s1 * 64 + lane];
        uint2 r2 = xb[(size_t)s2 * 64 + lane];
        uint2 r3 = xb[(size_t)s3 * 64 + lane];
        a0 += w0 * blo(r0.x) + w1 * blo(r1.x) + ww2 * blo(r2.x) + w3 * blo(r3.x);
        a1 += w0 * bhi(r0.x) + w1 * bhi(r1.x) + ww2 * bhi(r2.x) + w3 * bhi(r3.x);
        a2 += w0 * blo(r0.y) + w1 * blo(r1.y) + ww2 * blo(r2.y) + w3 * blo(r3.y);
        a3 += w0 * bhi(r0.y) + w1 * bhi(r1.y) + ww2 * bhi(r2.y) + w3 * bhi(r3.y);
    }
    for (; i < i1; ++i) {
        int s = csr[i];
        float w = dinv[s] * wn;
        uint2 r = xb[(size_t)s * 64 + lane];
        a0 += w * blo(r.x); a1 += w * bhi(r.x);
        a2 += w * blo(r.y); a3 += w * bhi(r.y);
    }
    uint2 o;
    o.x = (uint)f2b(a0) | ((uint)f2b(a1) << 16);
    o.y = (uint)f2b(a2) | ((uint)f2b(a3) << 16);
    agg_all[((size_t)g * NN + n) * 64 + lane] = o;
}

// ---------------- weight prep ----------------
__global__ void w_transpose_cast(const float* __restrict__ W, ushort* __restrict__ WT,
                                 int K, int N) {
    int i = blockIdx.x * blockDim.x + threadIdx.x;
    if (i < K * N) {
        int n = i / K, k = i - n * K;
        WT[i] = f2b(W[(size_t)k * N + n]);
    }
}

__global__ void pack_heads_w(const float* __restrict__ Wl, const float* __restrict__ Wv,
                             ushort* __restrict__ WT19) {
    int i = blockIdx.x * blockDim.x + threadIdx.x;
    if (i < 19 * FOUT) {
        int o = i >> 10, k = i & (FOUT - 1);
        WT19[i] = f2b((o < NLOG) ? Wl[(size_t)k * NLOG + o] : Wv[k]);
    }
}

// ---------------- MFMA GEMM (layer 1, batched via blockIdx.z) ----------------
__global__ __launch_bounds__(256) void mfma_gemm(
    const ushort* __restrict__ A_all, const ushort* __restrict__ BT,
    const float* __restrict__ bias, ushort* __restrict__ C_all,
    int M, int N, int K, int relu)
{
    __shared__ ushort As[128][72];
    __shared__ ushort Bs[128][72];

    int g = blockIdx.z;
    const ushort* A = A_all + (size_t)g * M * K;
    ushort* C = C_all + (size_t)g * M * N;

    int t = threadIdx.x;
    int bn = blockIdx.x, bm = blockIdx.y;
    int lane = t & 63, w = t >> 6;
    int wm = w >> 1, wn = w & 1;
    int l15 = lane & 15, quad = lane >> 4;

    f32x4 acc[4][4] = {};

    int srow = t >> 3, scol = (t & 7) * 8;
    const ushort* Abase = A + (size_t)(bm * 128) * K;
    const ushort* Bbase = BT + (size_t)(bn * 128) * K;

    for (int k0 = 0; k0 < K; k0 += 64) {
#pragma unroll
        for (int i = 0; i < 4; ++i) {
            int row = srow + 32 * i;
            *(uint4*)&As[row][scol] = *(const uint4*)(Abase + (size_t)row * K + k0 + scol);
        }
#pragma unroll
        for (int i = 0; i < 4; ++i) {
            int row = srow + 32 * i;
            *(uint4*)&Bs[row][scol] = *(const uint4*)(Bbase + (size_t)row * K + k0 + scol);
        }
        __syncthreads();
#pragma unroll
        for (int kk = 0; kk < 64; kk += 32) {
            frag8 af[4], bf[4];
#pragma unroll
            for (int i = 0; i < 4; ++i)
                af[i] = *(const frag8*)&As[wm * 64 + i * 16 + l15][kk + quad * 8];
#pragma unroll
            for (int j = 0; j < 4; ++j)
                bf[j] = *(const frag8*)&Bs[wn * 64 + j * 16 + l15][kk + quad * 8];
#pragma unroll
            for (int i = 0; i < 4; ++i)
#pragma unroll
                for (int j = 0; j < 4; ++j)
                    acc[i][j] = __builtin_amdgcn_mfma_f32_16x16x32_bf16(af[i], bf[j], acc[i][j], 0, 0, 0);
        }
        __syncthreads();
    }

#pragma unroll
    for (int i = 0; i < 4; ++i) {
#pragma unroll
        for (int j = 0; j < 4; ++j) {
            int col = bn * 128 + wn * 64 + j * 16 + l15;
            float bcol = bias[col];
#pragma unroll
            for (int r = 0; r < 4; ++r) {
                int row = bm * 128 + wm * 64 + i * 16 + quad * 4 + r;
                float v = acc[i][j][r] + bcol;
                if (relu) v = fmaxf(v, 0.0f);
                C[(size_t)row * N + col] = f2b(v);
            }
        }
    }
}

// ---------------- fused layer-2 GEMM + heads: h2 never hits HBM ----------------
// grid (bm=64, split=2, g=4). Block: 128 rows x (4 bn-tiles of 128 cols).
// Per bn: m97-style K-loop (K=256) -> C tile -> bias+relu+bf16 -> LDS Ctile
// (overlays As/Bs) -> 16 head MFMAs vs WT19 slice -> f32 partial acc in regs.
__global__ __launch_bounds__(256) void gemm2_heads(
    const ushort* __restrict__ hagg_all,  // [g][NN][FH] bf16
    const ushort* __restrict__ W1T,       // [FOUT][FH] bf16
    const float*  __restrict__ b1,        // [FOUT]
    const ushort* __restrict__ WT19,      // [19][FOUT] bf16
    float* __restrict__ partial)          // [2][BB][NN][P20] f32
{
    __shared__ __align__(16) ushort smem[2 * 128 * 72];  // As|Bs; reused as Ctile
    __shared__ __align__(16) ushort wt[20][136];         // WT19 slice, row19=0

    ushort* As = smem;               // [128][72]
    ushort* Bs = smem + 128 * 72;    // [128][72]
    ushort* Ct = smem;               // [128][136] bf16 (34816 <= 36864 shorts)

    int bm = blockIdx.x, sp = blockIdx.y, g = blockIdx.z;
    int t = threadIdx.x;
    int lane = t & 63, w = t >> 6;
    int wm = w >> 1, wn = w & 1;
    int l15 = lane & 15, quad = lane >> 4;
    int srow = t >> 3, scol = (t & 7) * 8;

    const ushort* A0 = hagg_all + ((size_t)g * NN + bm * 128) * FH;

    if (t < 136) wt[19][t] = 0;   // zero pad row once (never overwritten)

    f32x4 hacc[2][2] = {};        // [m-tile][o-tile] heads accumulators

    for (int bi = 0; bi < 4; ++bi) {
        int bn = sp * 4 + bi;
        __syncthreads();   // previous iter's heads reads of Ct/wt complete

        // stage WT19 slice rows 0..18 (cols bn*128..+128)
        for (int idx = t; idx < 19 * 16; idx += 256) {
            int row = idx >> 4, c8 = (idx & 15) * 8;
            *(uint4*)&wt[row][c8] = *(const uint4*)(WT19 + (size_t)row * FOUT + bn * 128 + c8);
        }

        f32x4 acc[4][4] = {};
        const ushort* Bbase = W1T + (size_t)(bn * 128) * FH;

        for (int k0 = 0; k0 < FH; k0 += 64) {
#pragma unroll
            for (int i = 0; i < 4; ++i) {
                int row = srow + 32 * i;
                *(uint4*)&As[row * 72 + scol] = *(const uint4*)(A0 + (size_t)row * FH + k0 + scol);
                *(uint4*)&Bs[row * 72 + scol] = *(const uint4*)(Bbase + (size_t)row * FH + k0 + scol);
            }
            __syncthreads();
#pragma unroll
            for (int kk = 0; kk < 64; kk += 32) {
                frag8 af[4], bf[4];
#pragma unroll
                for (int i = 0; i < 4; ++i)
                    af[i] = *(const frag8*)&As[(wm * 64 + i * 16 + l15) * 72 + kk + quad * 8];
#pragma unroll
                for (int j = 0; j < 4; ++j)
                    bf[j] = *(const frag8*)&Bs[(wn * 64 + j * 16 + l15) * 72 + kk + quad * 8];
#pragma unroll
                for (int i = 0; i < 4; ++i)
#pragma unroll
                    for (int j = 0; j < 4; ++j)
                        acc[i][j] = __builtin_amdgcn_mfma_f32_16x16x32_bf16(af[i], bf[j], acc[i][j], 0, 0, 0);
            }
            __syncthreads();   // all waves done reading As/Bs (also guards Ct overwrite)
        }

        // epilogue: bias + relu -> bf16 -> Ctile
#pragma unroll
        for (int j = 0; j < 4; ++j) {
            int colL = wn * 64 + j * 16 + l15;
            float bcol = b1[bn * 128 + colL];
#pragma unroll
            for (int i = 0; i < 4; ++i) {
                int rowL = wm * 64 + i * 16 + quad * 4;
#pragma unroll
                for (int r = 0; r < 4; ++r) {
                    float v = fmaxf(acc[i][j][r] + bcol, 0.0f);
                    Ct[(size_t)(rowL + r) * 136 + colL] = f2b(v);
                }
            }
        }
        __syncthreads();

        // heads: wave w owns m-tiles 2w, 2w+1 (16 rows each)
        int r1 = (l15 < 3) ? (16 + l15) : 19;
#pragma unroll
        for (int kk = 0; kk < 128; kk += 32) {
            frag8 b0 = *(const frag8*)&wt[l15][kk + quad * 8];
            frag8 bO = *(const frag8*)&wt[r1][kk + quad * 8];
#pragma unroll
            for (int mt = 0; mt < 2; ++mt) {
                int row = (w * 2 + mt) * 16 + l15;
                frag8 af = *(const frag8*)&Ct[(size_t)row * 136 + kk + quad * 8];
                hacc[mt][0] = __builtin_amdgcn_mfma_f32_16x16x32_bf16(af, b0, hacc[mt][0], 0, 0, 0);
                hacc[mt][1] = __builtin_amdgcn_mfma_f32_16x16x32_bf16(af, bO, hacc[mt][1], 0, 0, 0);
            }
        }
        // loop-top sync guards Ct/wt reuse
    }

    // store partials: D layout col=l15 (output o), row=quad*4+r
#pragma unroll
    for (int mt = 0; mt < 2; ++mt) {
#pragma unroll
        for (int r = 0; r < 4; ++r) {
            int node = bm * 128 + (w * 2 + mt) * 16 + quad * 4 + r;
            size_t base = ((size_t)(sp * BB + g) * NN + node) * P20;
            partial[base + l15] = hacc[mt][0][r];
            if (l15 < 3) partial[base + 16 + l15] = hacc[mt][1][r];
        }
    }
}

// ---------------- heads combine: out = p0 + p1 + bias ----------------
__global__ void heads_combine(const float* __restrict__ partial,
                              const float* __restrict__ bl, const float* __restrict__ bv,
                              float* __restrict__ out_logits, float* __restrict__ out_values) {
    int i = blockIdx.x * blockDim.x + threadIdx.x;   // over BB*NN*19
    if (i >= BB * NN * 19) return;
    int o = i % 19;
    int gn = i / 19;   // g*NN + n
    float v = partial[(size_t)gn * P20 + o] + partial[((size_t)BB * NN + gn) * P20 + o];
    if (o < NLOG) out_logits[(size_t)gn * NLOG + o] = v + bl[o];
    else          out_values[gn] = v + bv[0];
}

// ---------------- launcher ----------------
extern "C" void kernel_launch(void* const* d_in, const int* in_sizes, int n_in,
                              void* d_out, int out_size, void* d_ws, size_t ws_size,
                              hipStream_t stream) {
    const float* nodes = (const float*)d_in[0];
    const int*   edges = (const int*)d_in[1];
    const float* W0 = (const float*)d_in[2];
    const float* b0 = (const float*)d_in[3];
    const float* W1 = (const float*)d_in[4];
    const float* b1 = (const float*)d_in[5];
    const float* Wl = (const float*)d_in[6];
    const float* bl = (const float*)d_in[7];
    const float* Wv = (const float*)d_in[8];
    const float* bv = (const float*)d_in[9];

    float* out_logits = (float*)d_out;
    float* out_values = out_logits + (size_t)BB * NN * NLOG;

    char* ws = (char*)d_ws;
    int*    cnt     = (int*)(ws);                     // 128 KB [0, 128K)
    int*    offs    = (int*)(ws + (128 << 10));       // 132 KB [128K, 260K)  stride NN+1
    int*    cursor  = (int*)(ws + (260 << 10));       // 128 KB [260K, 388K)
    float*  dinv    = (float*)(ws + (388 << 10));     // 128 KB [388K, 516K)
    int*    csr_src = (int*)(ws + (516 << 10));       // 1 MB   [516K, 1540K)
    ushort* W0T     = (ushort*)(ws + (1540 << 10));   // 64 KB
    ushort* W1T     = (ushort*)(ws + (1604 << 10));   // 512 KB
    ushort* WT19    = (ushort*)(ws + (2116 << 10));   // 38 KB   (ends 2154K)
    ushort* xagg_b  = (ushort*)(ws + (4u << 20));     // 8 MB   [4M, 12M)   [B,N,128]
    ushort* h1b     = (ushort*)(ws + (12u << 20));    // 16 MB  [12M, 28M)  [B,N,256]
    ushort* hagg_b  = (ushort*)(ws + (28u << 20));    // 16 MB  [28M, 44M)  [B,N,256]
    float*  partial = (float*)(ws + (44u << 20));     // 5.25 MB [2,B,N,20] f32
    // total ~50 MB

    // weight prep
    w_transpose_cast<<<(FOBS * FH + 255) / 256, 256, 0, stream>>>(W0, W0T, FOBS, FH);
    w_transpose_cast<<<(FH * FOUT + 255) / 256, 256, 0, stream>>>(W1, W1T, FH, FOUT);
    pack_heads_w<<<(19 * FOUT + 255) / 256, 256, 0, stream>>>(Wl, Wv, WT19);

    // CSR build (all graphs)
    hipMemsetAsync(cnt, 0, (size_t)BB * NN * sizeof(int), stream);
    count_kernel<<<dim3(EE / 256, BB), 256, 0, stream>>>(edges, cnt);
    scan_kernel<<<BB, 1024, 0, stream>>>(cnt, offs, cursor, dinv);
    csr_fill<<<dim3(EE / 256, BB), 256, 0, stream>>>(edges, cursor, csr_src);

    // layer 1: h1 = relu((A_hat x) W0 + b0)
    gather_agg_f32<<<dim3(NN / 4, BB), 256, 0, stream>>>(nodes, offs, csr_src, dinv,
                                                         (uint*)xagg_b);
    mfma_gemm<<<dim3(FH / 128, NN / 128, BB), 256, 0, stream>>>(
        xagg_b, W0T, b0, h1b, NN, FH, FOBS, 1);

    // layer 2 aggregation
    gather_agg_bf16<<<dim3(NN / 4, BB), 256, 0, stream>>>((const uint2*)h1b, offs, csr_src,
                                                          dinv, (uint2*)hagg_b);

    // fused layer-2 GEMM + heads (h2 stays in LDS)
    gemm2_heads<<<dim3(NN / 128, 2, BB), 256, 0, stream>>>(hagg_b, W1T, b1, WT19, partial);
    heads_combine<<<(BB * NN * 19 + 255) / 256, 256, 0, stream>>>(partial, bl, bv,
                                                                  out_logits, out_values);
}